// Round 5
// baseline (310.738 us; speedup 1.0000x reference)
//
#include <hip/hip_runtime.h>
#include <hip/hip_bf16.h>

#define DEV static __device__ __forceinline__

DEV float silu(float x){ return x / (1.f + __expf(-x)); }

// ---- problem sizes ----
#define BB 4
#define LL 4096          // H*W, H=W=64
#define DM 96
#define DI 192
#define NS 16
#define KK 4
#define RR 6
#define C38 38
#define NC 64            // chunks
#define CL 64            // chunk length (CL=64 makes every scan direction a pure strided walk)

// ---- workspace layout (float offsets); total = 36,896,768 floats = 147.6 MB ----
#define OFF_XIN   0
#define OFF_Z     (OFF_XIN + BB*LL*DI)
#define OFF_XC    (OFF_Z + BB*LL*DI)
#define OFF_DELTA (OFF_XC + BB*LL*DI)
#define OFF_BC    (OFF_DELTA + BB*KK*LL*DI)
#define OFF_YS    (OFF_BC + BB*KK*LL*32)
#define OFF_S     (OFF_YS + BB*KK*LL*DI)
// hloc (BB*KK*NC*DI*NS = 3,145,728 floats) aliases XIN (dead after k_conv)
#define OFF_HLOC  OFF_XIN

// spatial position of sequence index t for scan direction k  (H=W=64)
DEV int pos_of(int k, int t){
    int pr = ((t & 63) << 6) | (t >> 6);
    int p  = (k & 1) ? pr : t;
    if (k & 2) p = LL - 1 - p;
    return p;
}

// ---- 1. in_proj: x(16384,96) @ W^T(384,96) -> xin(.,192), z(.,192) ----
__global__ __launch_bounds__(384) void k_inproj(const float* __restrict__ x, const float* __restrict__ w,
                                                float* __restrict__ xin, float* __restrict__ z){
    __shared__ float xs[8][96];
    int tid = threadIdx.x;
    int r0 = blockIdx.x * 8;
    const float* xrow = x + (long)r0 * DM;
    for (int i = tid; i < 8*96; i += 384) xs[i/96][i%96] = xrow[i];
    __syncthreads();
    int j = tid;                         // 0..383 output column
    const float* wr = w + (long)j * DM;
    float acc[8];
#pragma unroll
    for (int r = 0; r < 8; ++r) acc[r] = 0.f;
    for (int kk = 0; kk < DM; ++kk){
        float wv = wr[kk];
#pragma unroll
        for (int r = 0; r < 8; ++r) acc[r] += wv * xs[r][kk];
    }
    if (j < DI){
#pragma unroll
        for (int r = 0; r < 8; ++r) xin[(long)(r0 + r)*DI + j] = acc[r];
    } else {
        int jj = j - DI;
#pragma unroll
        for (int r = 0; r < 8; ++r) z[(long)(r0 + r)*DI + jj] = acc[r];
    }
}

// ---- 2. depthwise 3x3 conv (pad 1) + bias + SiLU, channels-last ----
__global__ __launch_bounds__(256) void k_conv(const float* __restrict__ xin, const float* __restrict__ cw,
                                              const float* __restrict__ cb, float* __restrict__ xc){
    int g = blockIdx.x * 256 + threadIdx.x;   // < BB*LL*DI
    int d = g % DI;
    int l = (g / DI) % LL;
    int b = g / (DI * LL);
    int h = l >> 6, ww = l & 63;
    float acc = cb[d];
    const float* base = xin + (long)b * LL * DI + d;
#pragma unroll
    for (int dy = 0; dy < 3; ++dy){
        int hh = h + dy - 1;
        if (hh < 0 || hh >= 64) continue;
#pragma unroll
        for (int dx = 0; dx < 3; ++dx){
            int wx = ww + dx - 1;
            if (wx < 0 || wx >= 64) continue;
            acc += base[(long)(hh*64 + wx)*DI] * cw[d*9 + dy*3 + dx];
        }
    }
    xc[g] = silu(acc);
}

// ---- 3. x_proj (38 outs) + dt_proj (rank 6) + softplus ----
// x-tile in LDS; W rows read from global (L2-hot, wave-broadcast) -> LDS pipe relieved
__global__ __launch_bounds__(256) void k_xdbl(const float* __restrict__ xc, const float* __restrict__ xpw,
                                              const float* __restrict__ dtw, const float* __restrict__ dtb,
                                              float* __restrict__ delta, float* __restrict__ bc2){
    __shared__ float xsT[192][33];    // 25.3KB: [d][t], conflict-free column reads
    __shared__ float ccs[32][41];     // 5.2KB
    __shared__ float dtws[192*6];     // 4.6KB   -> total ~35KB -> 4 blocks/CU
    int tid = threadIdx.x;
    int bk   = blockIdx.x >> 7;
    int tile = blockIdx.x & 127;
    int b = bk >> 2, k = bk & 3;
    int t0 = tile * 32;

    const float* dg = dtw + (long)k * DI * RR;
    for (int i = tid; i < DI*RR; i += 256) dtws[i] = dg[i];
    for (int i = tid; i < 32*DI; i += 256){
        int r = i / DI, d = i - r*DI;
        int p = pos_of(k, t0 + r);
        xsT[d][r] = xc[((long)b*LL + p)*DI + d];
    }
    __syncthreads();

    int t = tid & 31, cg = tid >> 5;          // c = cg + 8*jj, jj<5
    const float* wbase = xpw + (long)k * C38 * DI;
    const float* wp[5];
#pragma unroll
    for (int jj = 0; jj < 5; ++jj){
        int c = cg + 8*jj; if (c > 37) c = 37;   // clamp: invalid lanes read row 37, discarded
        wp[jj] = wbase + (long)c * DI;
    }
    float acc[5] = {0.f, 0.f, 0.f, 0.f, 0.f};
    for (int d = 0; d < DI; d += 4){
        float x0 = xsT[d+0][t], x1 = xsT[d+1][t], x2 = xsT[d+2][t], x3 = xsT[d+3][t];
#pragma unroll
        for (int jj = 0; jj < 5; ++jj){
            const float4 wv = *(const float4*)(wp[jj] + d);   // global, broadcast within half-wave
            acc[jj] += x0*wv.x + x1*wv.y + x2*wv.z + x3*wv.w;
        }
    }
#pragma unroll
    for (int jj = 0; jj < 5; ++jj){
        int c = cg + 8*jj;
        if (c < C38) ccs[t][c] = acc[jj];
    }
    __syncthreads();

    long obase = (long)bk * LL + t0;
    for (int i = tid; i < 32*DI; i += 256){
        int r = i / DI, d = i - r*DI;
        float raw = dtb[k*DI + d];
#pragma unroll
        for (int rr = 0; rr < RR; ++rr) raw += ccs[r][rr] * dtws[d*RR + rr];
        float sp = (raw > 15.f) ? raw : __logf(1.f + __expf(raw));
        delta[(obase + r)*DI + d] = sp;
    }
    for (int i = tid; i < 32*32; i += 256){
        int r = i >> 5, q = i & 31;
        bc2[(obase + r)*32 + q] = ccs[r][6 + q];
    }
}

// ---- 4. scan pass A: per-chunk local end-state (8 n-states/thread) + delta-sum ----
__global__ __launch_bounds__(192) void k_scanA(const float* __restrict__ delta, const float* __restrict__ bc2,
                                               const float* __restrict__ xc, const float* __restrict__ alog,
                                               float* __restrict__ hloc, float* __restrict__ Ssum){
    int tid = threadIdx.x;
    int j = tid & 1, dl = tid >> 1;
    int bid = blockIdx.x;
    int dg = bid & 1; int c = (bid >> 1) & 63; int bk = bid >> 7;
    int b = bk >> 2, k = bk & 3;
    int d = dg*96 + dl;
    int n0 = j*8;
    float a[8]; bool fast = true;
#pragma unroll
    for (int n = 0; n < 8; ++n){
        a[n] = -__expf(alog[(k*DI + d)*NS + n0 + n]);
        fast = fast && (fabsf(a[n] + (float)(n0 + n + 1)) < 1e-4f*(float)(n0 + n + 1));
    }
    int t0 = c * CL;
    int p0, st;
    if (k == 0){ p0 = t0;         st = 1;   }
    else if (k == 1){ p0 = c;     st = 64;  }
    else if (k == 2){ p0 = LL-1-t0; st = -1;  }
    else            { p0 = LL-1-c;  st = -64; }
    const float* dep = delta + ((long)bk*LL + t0)*DI + d;
    const float* bcp = bc2   + ((long)bk*LL + t0)*32 + n0;
    const float* up  = xc + ((long)b*LL + p0)*DI + d;
    long ustep = (long)st * DI;
    float h[8] = {0,0,0,0,0,0,0,0};
    float S = 0.f;
    if (fast){
        for (int i = 0; i < CL; ++i){
            float de = *dep;
            float u  = *up;
            float4 bv0 = *(const float4*)(bcp);
            float4 bv1 = *(const float4*)(bcp + 4);
            float E  = __expf(-de);
            float E2 = E*E, E4 = E2*E2, E8 = E4*E4;
            float e  = j ? E8 : 1.f;
            float du = de * u;
            S += de;
            float bb[8] = {bv0.x,bv0.y,bv0.z,bv0.w,bv1.x,bv1.y,bv1.z,bv1.w};
#pragma unroll
            for (int n = 0; n < 8; ++n){ e *= E; h[n] = h[n]*e + du*bb[n]; }
            dep += DI; up += ustep; bcp += 32;
        }
    } else {
        for (int i = 0; i < CL; ++i){
            float de = *dep;
            float u  = *up;
            float4 bv0 = *(const float4*)(bcp);
            float4 bv1 = *(const float4*)(bcp + 4);
            float du = de * u;
            S += de;
            float bb[8] = {bv0.x,bv0.y,bv0.z,bv0.w,bv1.x,bv1.y,bv1.z,bv1.w};
#pragma unroll
            for (int n = 0; n < 8; ++n){ float dA = __expf(de*a[n]); h[n] = h[n]*dA + du*bb[n]; }
            dep += DI; up += ustep; bcp += 32;
        }
    }
    long ho = (((long)bk*NC + c)*DI + d)*NS + n0;
    *(float4*)(hloc + ho)     = make_float4(h[0],h[1],h[2],h[3]);
    *(float4*)(hloc + ho + 4) = make_float4(h[4],h[5],h[6],h[7]);
    if (j == 0) Ssum[((long)bk*NC + c)*DI + d] = S;
}

// ---- 5. scan pass B: sequential chunk combine; hinit written in-place into hloc ----
__global__ __launch_bounds__(256) void k_scanB(float* __restrict__ hloc, const float* __restrict__ Ssum,
                                               const float* __restrict__ alog){
    int gid = blockIdx.x * 256 + threadIdx.x;       // < BB*KK*DI*NS = 49152
    int dn = gid % (DI*NS);
    int bk = gid / (DI*NS);
    int d = dn >> 4, n = dn & 15;
    int k = bk & 3;
    float a = -__expf(alog[(k*DI + d)*NS + n]);
    float h = 0.f;
    long base  = (long)bk * NC * DI * NS + dn;
    long sbase = (long)bk * NC * DI + d;
#pragma unroll 4
    for (int c = 0; c < NC; ++c){
        long o = base + (long)c * DI * NS;
        float P = __expf(a * Ssum[sbase + (long)c * DI]);
        float tmp = hloc[o];
        hloc[o] = h;
        h = h * P + tmp;
    }
}

// ---- 6. scan pass C: replay with correct initial state, emit y at SPATIAL position ----
__global__ __launch_bounds__(192) void k_scanC(const float* __restrict__ delta, const float* __restrict__ bc2,
                                               const float* __restrict__ xc, const float* __restrict__ alog,
                                               const float* __restrict__ hloc, float* __restrict__ ys){
    int tid = threadIdx.x;
    int j = tid & 1, dl = tid >> 1;
    int bid = blockIdx.x;
    int dg = bid & 1; int c = (bid >> 1) & 63; int bk = bid >> 7;
    int b = bk >> 2, k = bk & 3;
    int d = dg*96 + dl;
    int n0 = j*8;
    float a[8]; bool fast = true;
#pragma unroll
    for (int n = 0; n < 8; ++n){
        a[n] = -__expf(alog[(k*DI + d)*NS + n0 + n]);
        fast = fast && (fabsf(a[n] + (float)(n0 + n + 1)) < 1e-4f*(float)(n0 + n + 1));
    }
    int t0 = c * CL;
    int p0, st;
    if (k == 0){ p0 = t0;         st = 1;   }
    else if (k == 1){ p0 = c;     st = 64;  }
    else if (k == 2){ p0 = LL-1-t0; st = -1;  }
    else            { p0 = LL-1-c;  st = -64; }
    const float* dep = delta + ((long)bk*LL + t0)*DI + d;
    const float* bcp = bc2   + ((long)bk*LL + t0)*32 + n0;
    const float* up  = xc + ((long)b*LL + p0)*DI + d;
    float*       yp  = ys + ((long)bk*LL + p0)*DI + d;
    long ustep = (long)st * DI;
    long ho = (((long)bk*NC + c)*DI + d)*NS + n0;
    float4 h03 = *(const float4*)(hloc + ho);
    float4 h47 = *(const float4*)(hloc + ho + 4);
    float h[8] = {h03.x,h03.y,h03.z,h03.w,h47.x,h47.y,h47.z,h47.w};
    if (fast){
        for (int i = 0; i < CL; ++i){
            float de = *dep;
            float u  = *up;
            float4 bv0 = *(const float4*)(bcp);
            float4 bv1 = *(const float4*)(bcp + 4);
            float4 cv0 = *(const float4*)(bcp + 16);
            float4 cv1 = *(const float4*)(bcp + 20);
            float E  = __expf(-de);
            float E2 = E*E, E4 = E2*E2, E8 = E4*E4;
            float e  = j ? E8 : 1.f;
            float du = de * u;
            float bb[8] = {bv0.x,bv0.y,bv0.z,bv0.w,bv1.x,bv1.y,bv1.z,bv1.w};
            float cc[8] = {cv0.x,cv0.y,cv0.z,cv0.w,cv1.x,cv1.y,cv1.z,cv1.w};
            float y = 0.f;
#pragma unroll
            for (int n = 0; n < 8; ++n){ e *= E; h[n] = h[n]*e + du*bb[n]; y += h[n]*cc[n]; }
            y += __shfl_xor(y, 1, 64);
            if (j == 0) *yp = y;
            dep += DI; up += ustep; yp += ustep; bcp += 32;
        }
    } else {
        for (int i = 0; i < CL; ++i){
            float de = *dep;
            float u  = *up;
            float4 bv0 = *(const float4*)(bcp);
            float4 bv1 = *(const float4*)(bcp + 4);
            float4 cv0 = *(const float4*)(bcp + 16);
            float4 cv1 = *(const float4*)(bcp + 20);
            float du = de * u;
            float bb[8] = {bv0.x,bv0.y,bv0.z,bv0.w,bv1.x,bv1.y,bv1.z,bv1.w};
            float cc[8] = {cv0.x,cv0.y,cv0.z,cv0.w,cv1.x,cv1.y,cv1.z,cv1.w};
            float y = 0.f;
#pragma unroll
            for (int n = 0; n < 8; ++n){ float dA = __expf(de*a[n]); h[n] = h[n]*dA + du*bb[n]; y += h[n]*cc[n]; }
            y += __shfl_xor(y, 1, 64);
            if (j == 0) *yp = y;
            dep += DI; up += ustep; yp += ustep; bcp += 32;
        }
    }
}

// ---- 7. merge(4 dirs) + D*u skip + LayerNorm + SiLU gate + out_proj -> fp32 out ----
__global__ __launch_bounds__(192) void k_fuse(const float* __restrict__ ys, const float* __restrict__ xc,
                                              const float* __restrict__ z, const float* __restrict__ Dsk,
                                              const float* __restrict__ lnw, const float* __restrict__ lnb,
                                              const float* __restrict__ wout, float* __restrict__ out){
    __shared__ float yv[4][DI];
    __shared__ float red[2][3];
    __shared__ float part[2][4][96];
    int tid = threadIdx.x;
    int b  = blockIdx.x / (LL/4);
    int p0 = (blockIdx.x % (LL/4)) * 4;
    int d = tid;
    float sumD = Dsk[d] + Dsk[DI + d] + Dsk[2*DI + d] + Dsk[3*DI + d];
    float lw = lnw[d], lb = lnb[d];
    for (int pp = 0; pp < 4; ++pp){
        int p = p0 + pp;
        long yb = ((long)b*4)*LL*DI + (long)p*DI + d;
        float y = ys[yb] + ys[yb + (long)LL*DI] + ys[yb + 2L*LL*DI] + ys[yb + 3L*LL*DI];
        y += xc[((long)b*LL + p)*DI + d] * sumD;
        float s = y, sq = y*y;
#pragma unroll
        for (int m = 32; m > 0; m >>= 1){ s += __shfl_down(s, m, 64); sq += __shfl_down(sq, m, 64); }
        int wvi = tid >> 6, ln = tid & 63;
        if (ln == 0){ red[0][wvi] = s; red[1][wvi] = sq; }
        __syncthreads();
        float st  = red[0][0] + red[0][1] + red[0][2];
        float sqt = red[1][0] + red[1][1] + red[1][2];
        float mu  = st / DI;
        float var = sqt / DI - mu*mu;
        float rs  = rsqrtf(var + 1e-5f);
        float yn  = (y - mu)*rs*lw + lb;
        float zg  = z[((long)b*LL + p)*DI + d];
        yv[pp][d] = yn * silu(zg);
        __syncthreads();
    }
    int m = tid % 96, half = tid / 96;
    float acc[4] = {0.f, 0.f, 0.f, 0.f};
    const float* wr = wout + (long)m*DI + half*96;
    for (int dd = 0; dd < 96; ++dd){
        float wv = wr[dd];
        int df = half*96 + dd;
#pragma unroll
        for (int pp = 0; pp < 4; ++pp) acc[pp] += wv * yv[pp][df];
    }
#pragma unroll
    for (int pp = 0; pp < 4; ++pp) part[half][pp][m] = acc[pp];
    __syncthreads();
    if (tid < 96){
#pragma unroll
        for (int pp = 0; pp < 4; ++pp){
            float v = part[0][pp][tid] + part[1][pp][tid];
            out[((long)b*LL + p0 + pp)*DM + tid] = v;
        }
    }
}

extern "C" void kernel_launch(void* const* d_in, const int* in_sizes, int n_in,
                              void* d_out, int out_size, void* d_ws, size_t ws_size,
                              hipStream_t stream){
    (void)in_sizes; (void)n_in; (void)out_size; (void)ws_size;
    const float* x    = (const float*)d_in[0];
    const float* win  = (const float*)d_in[1];
    const float* cw   = (const float*)d_in[2];
    const float* cb   = (const float*)d_in[3];
    const float* xpw  = (const float*)d_in[4];
    const float* dtw  = (const float*)d_in[5];
    const float* dtb  = (const float*)d_in[6];
    const float* alog = (const float*)d_in[7];
    const float* ds   = (const float*)d_in[8];
    const float* lnw  = (const float*)d_in[9];
    const float* lnb  = (const float*)d_in[10];
    const float* wout = (const float*)d_in[11];

    float* ws    = (float*)d_ws;
    float* xin   = ws + OFF_XIN;
    float* z     = ws + OFF_Z;
    float* xc    = ws + OFF_XC;
    float* delta = ws + OFF_DELTA;
    float* bc2   = ws + OFF_BC;
    float* ysb   = ws + OFF_YS;
    float* Ssum  = ws + OFF_S;
    float* hloc  = ws + OFF_HLOC;   // aliases xin (dead after k_conv)

    k_inproj<<<dim3(2048), dim3(384), 0, stream>>>(x, win, xin, z);
    k_conv  <<<dim3(12288), dim3(256), 0, stream>>>(xin, cw, cb, xc);
    k_xdbl  <<<dim3(2048), dim3(256), 0, stream>>>(xc, xpw, dtw, dtb, delta, bc2);
    k_scanA <<<dim3(2048), dim3(192), 0, stream>>>(delta, bc2, xc, alog, hloc, Ssum);
    k_scanB <<<dim3(192),  dim3(256), 0, stream>>>(hloc, Ssum, alog);
    k_scanC <<<dim3(2048), dim3(192), 0, stream>>>(delta, bc2, xc, alog, hloc, ysb);
    k_fuse  <<<dim3(4096), dim3(192), 0, stream>>>(ysb, xc, z, ds, lnw, lnb, wout,
                                                   (float*)d_out);
}

// Round 6
// 302.573 us; speedup vs baseline: 1.0270x; 1.0270x over previous
//
#include <hip/hip_runtime.h>
#include <hip/hip_bf16.h>

#define DEV static __device__ __forceinline__

DEV float silu(float x){ return x / (1.f + __expf(-x)); }

typedef __attribute__((ext_vector_type(8))) short bf16x8;
typedef __attribute__((ext_vector_type(4))) float f32x4;

DEV unsigned short f2bf(float f){
    unsigned u = __float_as_uint(f);
    u += 0x7FFF + ((u >> 16) & 1);      // RNE
    return (unsigned short)(u >> 16);
}

// ---- problem sizes ----
#define BB 4
#define LL 4096          // H*W, H=W=64
#define DM 96
#define DI 192
#define NS 16
#define KK 4
#define RR 6
#define C38 38
#define NC 64            // chunks
#define CL 64            // chunk length

// ---- workspace layout (float offsets); total = 36,896,768 floats = 147.6 MB ----
#define OFF_XIN   0
#define OFF_Z     (OFF_XIN + BB*LL*DI)
#define OFF_XC    (OFF_Z + BB*LL*DI)
#define OFF_DELTA (OFF_XC + BB*LL*DI)
#define OFF_BC    (OFF_DELTA + BB*KK*LL*DI)
#define OFF_YS    (OFF_BC + BB*KK*LL*32)
#define OFF_S     (OFF_YS + BB*KK*LL*DI)
#define OFF_HLOC  OFF_XIN   // hloc aliases XIN (dead after k_conv)

// spatial position of sequence index t for scan direction k  (H=W=64)
DEV int pos_of(int k, int t){
    int pr = ((t & 63) << 6) | (t >> 6);
    int p  = (k & 1) ? pr : t;
    if (k & 2) p = LL - 1 - p;
    return p;
}

// ---- 1. in_proj ----
__global__ __launch_bounds__(384) void k_inproj(const float* __restrict__ x, const float* __restrict__ w,
                                                float* __restrict__ xin, float* __restrict__ z){
    __shared__ float xs[8][96];
    int tid = threadIdx.x;
    int r0 = blockIdx.x * 8;
    const float* xrow = x + (long)r0 * DM;
    for (int i = tid; i < 8*96; i += 384) xs[i/96][i%96] = xrow[i];
    __syncthreads();
    int j = tid;
    const float* wr = w + (long)j * DM;
    float acc[8];
#pragma unroll
    for (int r = 0; r < 8; ++r) acc[r] = 0.f;
    for (int kk = 0; kk < DM; ++kk){
        float wv = wr[kk];
#pragma unroll
        for (int r = 0; r < 8; ++r) acc[r] += wv * xs[r][kk];
    }
    if (j < DI){
#pragma unroll
        for (int r = 0; r < 8; ++r) xin[(long)(r0 + r)*DI + j] = acc[r];
    } else {
        int jj = j - DI;
#pragma unroll
        for (int r = 0; r < 8; ++r) z[(long)(r0 + r)*DI + jj] = acc[r];
    }
}

// ---- 2. depthwise 3x3 conv + bias + SiLU ----
__global__ __launch_bounds__(256) void k_conv(const float* __restrict__ xin, const float* __restrict__ cw,
                                              const float* __restrict__ cb, float* __restrict__ xc){
    int g = blockIdx.x * 256 + threadIdx.x;
    int d = g % DI;
    int l = (g / DI) % LL;
    int b = g / (DI * LL);
    int h = l >> 6, ww = l & 63;
    float acc = cb[d];
    const float* base = xin + (long)b * LL * DI + d;
#pragma unroll
    for (int dy = 0; dy < 3; ++dy){
        int hh = h + dy - 1;
        if (hh < 0 || hh >= 64) continue;
#pragma unroll
        for (int dx = 0; dx < 3; ++dx){
            int wx = ww + dx - 1;
            if (wx < 0 || wx >= 64) continue;
            acc += base[(long)(hh*64 + wx)*DI] * cw[d*9 + dy*3 + dx];
        }
    }
    xc[g] = silu(acc);
}

// ---- 3. x_proj + dt_proj + softplus — bf16 MFMA GEMM ----
// block = one (b,k) x 64 time steps; 4 waves, each: 16t x 48c via mfma_f32_16x16x32_bf16
#define XP 200   // bf16 row stride: 400B (16B aligned; 2-way bank alias only)
__global__ __launch_bounds__(256) void k_xdbl(const float* __restrict__ xc, const float* __restrict__ xpw,
                                              const float* __restrict__ dtw, const float* __restrict__ dtb,
                                              float* __restrict__ delta, float* __restrict__ bc2){
    __shared__ unsigned short xsb[64*XP];   // 25.6KB  xs tile (64 t x 192 d) bf16
    __shared__ unsigned short wsb[48*XP];   // 19.2KB  W rows (38 real, 48 padded w/ zeros) bf16
    __shared__ float ccs[64][40];           // 10.2KB
    __shared__ float dtws[DI*RR];           // 4.6KB
    int tid = threadIdx.x;
    int bk   = blockIdx.x >> 6;
    int tile = blockIdx.x & 63;
    int b = bk >> 2, k = bk & 3;
    int t0 = tile * 64;

    const float* wg = xpw + (long)k * C38 * DI;
    for (int i = tid; i < 48*DI; i += 256){
        int c = i / DI, d = i - c*DI;
        wsb[c*XP + d] = (c < C38) ? f2bf(wg[c*DI + d]) : (unsigned short)0;
    }
    const float* dg = dtw + (long)k * DI * RR;
    for (int i = tid; i < DI*RR; i += 256) dtws[i] = dg[i];
    for (int i = tid; i < 64*DI; i += 256){
        int r = i / DI, d = i - r*DI;
        int p = pos_of(k, t0 + r);
        xsb[r*XP + d] = f2bf(xc[((long)b*LL + p)*DI + d]);
    }
    __syncthreads();

    int wv = tid >> 6, l = tid & 63;
    int lrow = l & 15, kgrp = l >> 4;
    f32x4 acc0 = {0,0,0,0}, acc1 = {0,0,0,0}, acc2 = {0,0,0,0};
    const unsigned short* xrow = &xsb[(wv*16 + lrow)*XP + kgrp*8];  // A: row=t, k
    const unsigned short* wrow = &wsb[lrow*XP + kgrp*8];            // B: col=c, k
#pragma unroll
    for (int kk = 0; kk < 6; ++kk){
        bf16x8 af = *(const bf16x8*)(xrow + kk*32);
        bf16x8 b0 = *(const bf16x8*)(wrow + kk*32);
        bf16x8 b1 = *(const bf16x8*)(wrow + 16*XP + kk*32);
        bf16x8 b2 = *(const bf16x8*)(wrow + 32*XP + kk*32);
        acc0 = __builtin_amdgcn_mfma_f32_16x16x32_bf16(af, b0, acc0, 0,0,0);
        acc1 = __builtin_amdgcn_mfma_f32_16x16x32_bf16(af, b1, acc1, 0,0,0);
        acc2 = __builtin_amdgcn_mfma_f32_16x16x32_bf16(af, b2, acc2, 0,0,0);
    }
    // C/D: col = l&15, row = (l>>4)*4 + reg  (row = t-local, col = c)
#pragma unroll
    for (int reg = 0; reg < 4; ++reg){
        int tl = wv*16 + kgrp*4 + reg;
        ccs[tl][lrow] = acc0[reg];
        ccs[tl][16 + lrow] = acc1[reg];
        if (lrow < 6) ccs[tl][32 + lrow] = acc2[reg];
    }
    __syncthreads();

    long obase = (long)bk * LL + t0;
    for (int i = tid; i < 64*DI; i += 256){
        int r = i / DI, d = i - r*DI;
        float raw = dtb[k*DI + d];
#pragma unroll
        for (int rr = 0; rr < RR; ++rr) raw += ccs[r][rr] * dtws[d*RR + rr];
        float sp = (raw > 15.f) ? raw : __logf(1.f + __expf(raw));
        delta[(obase + r)*DI + d] = sp;
    }
    for (int i = tid; i < 64*32; i += 256){
        int r = i >> 5, q = i & 31;
        bc2[(obase + r)*32 + q] = ccs[r][6 + q];
    }
}

// ---- 4. scan pass A ----
__global__ __launch_bounds__(192) void k_scanA(const float* __restrict__ delta, const float* __restrict__ bc2,
                                               const float* __restrict__ xc, const float* __restrict__ alog,
                                               float* __restrict__ hloc, float* __restrict__ Ssum){
    int tid = threadIdx.x;
    int j = tid & 1, dl = tid >> 1;
    int bid = blockIdx.x;
    int dg = bid & 1; int c = (bid >> 1) & 63; int bk = bid >> 7;
    int b = bk >> 2, k = bk & 3;
    int d = dg*96 + dl;
    int n0 = j*8;
    float a[8]; bool fast = true;
#pragma unroll
    for (int n = 0; n < 8; ++n){
        a[n] = -__expf(alog[(k*DI + d)*NS + n0 + n]);
        fast = fast && (fabsf(a[n] + (float)(n0 + n + 1)) < 1e-4f*(float)(n0 + n + 1));
    }
    int t0 = c * CL;
    int p0, st;
    if (k == 0){ p0 = t0;         st = 1;   }
    else if (k == 1){ p0 = c;     st = 64;  }
    else if (k == 2){ p0 = LL-1-t0; st = -1;  }
    else            { p0 = LL-1-c;  st = -64; }
    const float* dep = delta + ((long)bk*LL + t0)*DI + d;
    const float* bcp = bc2   + ((long)bk*LL + t0)*32 + n0;
    const float* up  = xc + ((long)b*LL + p0)*DI + d;
    long ustep = (long)st * DI;
    float h[8] = {0,0,0,0,0,0,0,0};
    float S = 0.f;
    if (fast){
        for (int i = 0; i < CL; ++i){
            float de = *dep;
            float u  = *up;
            float4 bv0 = *(const float4*)(bcp);
            float4 bv1 = *(const float4*)(bcp + 4);
            float E  = __expf(-de);
            float E2 = E*E, E4 = E2*E2, E8 = E4*E4;
            float e  = j ? E8 : 1.f;
            float du = de * u;
            S += de;
            float bb[8] = {bv0.x,bv0.y,bv0.z,bv0.w,bv1.x,bv1.y,bv1.z,bv1.w};
#pragma unroll
            for (int n = 0; n < 8; ++n){ e *= E; h[n] = h[n]*e + du*bb[n]; }
            dep += DI; up += ustep; bcp += 32;
        }
    } else {
        for (int i = 0; i < CL; ++i){
            float de = *dep;
            float u  = *up;
            float4 bv0 = *(const float4*)(bcp);
            float4 bv1 = *(const float4*)(bcp + 4);
            float du = de * u;
            S += de;
            float bb[8] = {bv0.x,bv0.y,bv0.z,bv0.w,bv1.x,bv1.y,bv1.z,bv1.w};
#pragma unroll
            for (int n = 0; n < 8; ++n){ float dA = __expf(de*a[n]); h[n] = h[n]*dA + du*bb[n]; }
            dep += DI; up += ustep; bcp += 32;
        }
    }
    long ho = (((long)bk*NC + c)*DI + d)*NS + n0;
    *(float4*)(hloc + ho)     = make_float4(h[0],h[1],h[2],h[3]);
    *(float4*)(hloc + ho + 4) = make_float4(h[4],h[5],h[6],h[7]);
    if (j == 0) Ssum[((long)bk*NC + c)*DI + d] = S;
}

// ---- 5. scan pass B ----
__global__ __launch_bounds__(256) void k_scanB(float* __restrict__ hloc, const float* __restrict__ Ssum,
                                               const float* __restrict__ alog){
    int gid = blockIdx.x * 256 + threadIdx.x;
    int dn = gid % (DI*NS);
    int bk = gid / (DI*NS);
    int d = dn >> 4, n = dn & 15;
    int k = bk & 3;
    float a = -__expf(alog[(k*DI + d)*NS + n]);
    float h = 0.f;
    long base  = (long)bk * NC * DI * NS + dn;
    long sbase = (long)bk * NC * DI + d;
#pragma unroll 4
    for (int c = 0; c < NC; ++c){
        long o = base + (long)c * DI * NS;
        float P = __expf(a * Ssum[sbase + (long)c * DI]);
        float tmp = hloc[o];
        hloc[o] = h;
        h = h * P + tmp;
    }
}

// ---- 6. scan pass C ----
__global__ __launch_bounds__(192) void k_scanC(const float* __restrict__ delta, const float* __restrict__ bc2,
                                               const float* __restrict__ xc, const float* __restrict__ alog,
                                               const float* __restrict__ hloc, float* __restrict__ ys){
    int tid = threadIdx.x;
    int j = tid & 1, dl = tid >> 1;
    int bid = blockIdx.x;
    int dg = bid & 1; int c = (bid >> 1) & 63; int bk = bid >> 7;
    int b = bk >> 2, k = bk & 3;
    int d = dg*96 + dl;
    int n0 = j*8;
    float a[8]; bool fast = true;
#pragma unroll
    for (int n = 0; n < 8; ++n){
        a[n] = -__expf(alog[(k*DI + d)*NS + n0 + n]);
        fast = fast && (fabsf(a[n] + (float)(n0 + n + 1)) < 1e-4f*(float)(n0 + n + 1));
    }
    int t0 = c * CL;
    int p0, st;
    if (k == 0){ p0 = t0;         st = 1;   }
    else if (k == 1){ p0 = c;     st = 64;  }
    else if (k == 2){ p0 = LL-1-t0; st = -1;  }
    else            { p0 = LL-1-c;  st = -64; }
    const float* dep = delta + ((long)bk*LL + t0)*DI + d;
    const float* bcp = bc2   + ((long)bk*LL + t0)*32 + n0;
    const float* up  = xc + ((long)b*LL + p0)*DI + d;
    float*       yp  = ys + ((long)bk*LL + p0)*DI + d;
    long ustep = (long)st * DI;
    long ho = (((long)bk*NC + c)*DI + d)*NS + n0;
    float4 h03 = *(const float4*)(hloc + ho);
    float4 h47 = *(const float4*)(hloc + ho + 4);
    float h[8] = {h03.x,h03.y,h03.z,h03.w,h47.x,h47.y,h47.z,h47.w};
    if (fast){
        for (int i = 0; i < CL; ++i){
            float de = *dep;
            float u  = *up;
            float4 bv0 = *(const float4*)(bcp);
            float4 bv1 = *(const float4*)(bcp + 4);
            float4 cv0 = *(const float4*)(bcp + 16);
            float4 cv1 = *(const float4*)(bcp + 20);
            float E  = __expf(-de);
            float E2 = E*E, E4 = E2*E2, E8 = E4*E4;
            float e  = j ? E8 : 1.f;
            float du = de * u;
            float bb[8] = {bv0.x,bv0.y,bv0.z,bv0.w,bv1.x,bv1.y,bv1.z,bv1.w};
            float cc[8] = {cv0.x,cv0.y,cv0.z,cv0.w,cv1.x,cv1.y,cv1.z,cv1.w};
            float y = 0.f;
#pragma unroll
            for (int n = 0; n < 8; ++n){ e *= E; h[n] = h[n]*e + du*bb[n]; y += h[n]*cc[n]; }
            y += __shfl_xor(y, 1, 64);
            if (j == 0) *yp = y;
            dep += DI; up += ustep; yp += ustep; bcp += 32;
        }
    } else {
        for (int i = 0; i < CL; ++i){
            float de = *dep;
            float u  = *up;
            float4 bv0 = *(const float4*)(bcp);
            float4 bv1 = *(const float4*)(bcp + 4);
            float4 cv0 = *(const float4*)(bcp + 16);
            float4 cv1 = *(const float4*)(bcp + 20);
            float du = de * u;
            float bb[8] = {bv0.x,bv0.y,bv0.z,bv0.w,bv1.x,bv1.y,bv1.z,bv1.w};
            float cc[8] = {cv0.x,cv0.y,cv0.z,cv0.w,cv1.x,cv1.y,cv1.z,cv1.w};
            float y = 0.f;
#pragma unroll
            for (int n = 0; n < 8; ++n){ float dA = __expf(de*a[n]); h[n] = h[n]*dA + du*bb[n]; y += h[n]*cc[n]; }
            y += __shfl_xor(y, 1, 64);
            if (j == 0) *yp = y;
            dep += DI; up += ustep; yp += ustep; bcp += 32;
        }
    }
}

// ---- 7. merge + LN + gate + out_proj ----
__global__ __launch_bounds__(192) void k_fuse(const float* __restrict__ ys, const float* __restrict__ xc,
                                              const float* __restrict__ z, const float* __restrict__ Dsk,
                                              const float* __restrict__ lnw, const float* __restrict__ lnb,
                                              const float* __restrict__ wout, float* __restrict__ out){
    __shared__ float yv[4][DI];
    __shared__ float red[2][3];
    __shared__ float part[2][4][96];
    int tid = threadIdx.x;
    int b  = blockIdx.x / (LL/4);
    int p0 = (blockIdx.x % (LL/4)) * 4;
    int d = tid;
    float sumD = Dsk[d] + Dsk[DI + d] + Dsk[2*DI + d] + Dsk[3*DI + d];
    float lw = lnw[d], lb = lnb[d];
    for (int pp = 0; pp < 4; ++pp){
        int p = p0 + pp;
        long yb = ((long)b*4)*LL*DI + (long)p*DI + d;
        float y = ys[yb] + ys[yb + (long)LL*DI] + ys[yb + 2L*LL*DI] + ys[yb + 3L*LL*DI];
        y += xc[((long)b*LL + p)*DI + d] * sumD;
        float s = y, sq = y*y;
#pragma unroll
        for (int m = 32; m > 0; m >>= 1){ s += __shfl_down(s, m, 64); sq += __shfl_down(sq, m, 64); }
        int wvi = tid >> 6, ln = tid & 63;
        if (ln == 0){ red[0][wvi] = s; red[1][wvi] = sq; }
        __syncthreads();
        float st  = red[0][0] + red[0][1] + red[0][2];
        float sqt = red[1][0] + red[1][1] + red[1][2];
        float mu  = st / DI;
        float var = sqt / DI - mu*mu;
        float rs  = rsqrtf(var + 1e-5f);
        float yn  = (y - mu)*rs*lw + lb;
        float zg  = z[((long)b*LL + p)*DI + d];
        yv[pp][d] = yn * silu(zg);
        __syncthreads();
    }
    int m = tid % 96, half = tid / 96;
    float acc[4] = {0.f, 0.f, 0.f, 0.f};
    const float* wr = wout + (long)m*DI + half*96;
    for (int dd = 0; dd < 96; ++dd){
        float wv = wr[dd];
        int df = half*96 + dd;
#pragma unroll
        for (int pp = 0; pp < 4; ++pp) acc[pp] += wv * yv[pp][df];
    }
#pragma unroll
    for (int pp = 0; pp < 4; ++pp) part[half][pp][m] = acc[pp];
    __syncthreads();
    if (tid < 96){
#pragma unroll
        for (int pp = 0; pp < 4; ++pp){
            float v = part[0][pp][tid] + part[1][pp][tid];
            out[((long)b*LL + p0 + pp)*DM + tid] = v;
        }
    }
}

extern "C" void kernel_launch(void* const* d_in, const int* in_sizes, int n_in,
                              void* d_out, int out_size, void* d_ws, size_t ws_size,
                              hipStream_t stream){
    (void)in_sizes; (void)n_in; (void)out_size; (void)ws_size;
    const float* x    = (const float*)d_in[0];
    const float* win  = (const float*)d_in[1];
    const float* cw   = (const float*)d_in[2];
    const float* cb   = (const float*)d_in[3];
    const float* xpw  = (const float*)d_in[4];
    const float* dtw  = (const float*)d_in[5];
    const float* dtb  = (const float*)d_in[6];
    const float* alog = (const float*)d_in[7];
    const float* ds   = (const float*)d_in[8];
    const float* lnw  = (const float*)d_in[9];
    const float* lnb  = (const float*)d_in[10];
    const float* wout = (const float*)d_in[11];

    float* ws    = (float*)d_ws;
    float* xin   = ws + OFF_XIN;
    float* z     = ws + OFF_Z;
    float* xc    = ws + OFF_XC;
    float* delta = ws + OFF_DELTA;
    float* bc2   = ws + OFF_BC;
    float* ysb   = ws + OFF_YS;
    float* Ssum  = ws + OFF_S;
    float* hloc  = ws + OFF_HLOC;

    k_inproj<<<dim3(2048), dim3(384), 0, stream>>>(x, win, xin, z);
    k_conv  <<<dim3(12288), dim3(256), 0, stream>>>(xin, cw, cb, xc);
    k_xdbl  <<<dim3(1024), dim3(256), 0, stream>>>(xc, xpw, dtw, dtb, delta, bc2);
    k_scanA <<<dim3(2048), dim3(192), 0, stream>>>(delta, bc2, xc, alog, hloc, Ssum);
    k_scanB <<<dim3(192),  dim3(256), 0, stream>>>(hloc, Ssum, alog);
    k_scanC <<<dim3(2048), dim3(192), 0, stream>>>(delta, bc2, xc, alog, hloc, ysb);
    k_fuse  <<<dim3(4096), dim3(192), 0, stream>>>(ysb, xc, z, ds, lnw, lnb, wout,
                                                   (float*)d_out);
}

// Round 7
// 259.639 us; speedup vs baseline: 1.1968x; 1.1654x over previous
//
#include <hip/hip_runtime.h>
#include <hip/hip_bf16.h>

#define DEV static __device__ __forceinline__

DEV float silu(float x){ return x / (1.f + __expf(-x)); }

typedef __attribute__((ext_vector_type(8))) short bf16x8;
typedef __attribute__((ext_vector_type(4))) float f32x4;

DEV unsigned short f2bf(float f){
    unsigned u = __float_as_uint(f);
    u += 0x7FFF + ((u >> 16) & 1);      // RNE
    return (unsigned short)(u >> 16);
}

// ---- problem sizes ----
#define BB 4
#define LL 4096          // H*W, H=W=64
#define DM 96
#define DI 192
#define NS 16
#define KK 4
#define RR 6
#define C38 38
#define NC 64            // chunks
#define CL 64            // chunk length

// ---- workspace layout (float offsets) ----
#define OFF_XIN   0
#define OFF_Z     (OFF_XIN + BB*LL*DI)
#define OFF_XC    (OFF_Z + BB*LL*DI)
#define OFF_DELTA (OFF_XC + BB*LL*DI)
#define OFF_BC    (OFF_DELTA + BB*KK*LL*DI)
#define OFF_YS    (OFF_BC + BB*KK*LL*32)
#define OFF_S     (OFF_YS + BB*KK*LL*DI)
#define OFF_WB    (OFF_S + BB*KK*NC*DI)     // bf16 in_proj weights: 384*96 u16 = 18432 float slots
#define OFF_CWT   (OFF_WB + 18432)          // transposed conv weights: 9*192 floats
#define OFF_HLOC  OFF_XIN   // hloc aliases XIN (dead after k_conv)

// spatial position of sequence index t for scan direction k  (H=W=64)
DEV int pos_of(int k, int t){
    int pr = ((t & 63) << 6) | (t >> 6);
    int p  = (k & 1) ? pr : t;
    if (k & 2) p = LL - 1 - p;
    return p;
}

// ---- 0. prep: W_in -> bf16; conv weights -> [tap][d] ----
__global__ __launch_bounds__(256) void k_prep(const float* __restrict__ win, const float* __restrict__ cw,
                                              unsigned short* __restrict__ winb, float* __restrict__ cwT){
    int i = blockIdx.x * 256 + threadIdx.x;
    if (i < 384*DM) winb[i] = f2bf(win[i]);
    if (i < 9*DI){ int tap = i / DI, d = i - tap*DI; cwT[i] = cw[d*9 + tap]; }
}

// ---- 1. in_proj: bf16 MFMA GEMM. block = 16 rows x 384 cols, 4 waves (each 96 cols) ----
__global__ __launch_bounds__(256) void k_inproj(const float* __restrict__ x, const unsigned short* __restrict__ winb,
                                                float* __restrict__ xin, float* __restrict__ z){
    __shared__ unsigned short xsb[16*104];   // 16 rows x 96 k, stride 104
    int tid = threadIdx.x;
    int r0 = blockIdx.x * 16;
    const float* xrow = x + (long)r0 * DM;
    for (int i = tid; i < 16*DM; i += 256){
        int r = i / DM, d = i - r*DM;
        xsb[r*104 + d] = f2bf(xrow[i]);
    }
    __syncthreads();
    int wv = tid >> 6, l = tid & 63;
    int lrow = l & 15, kg = l >> 4;
    int nc0 = wv * 96;
    f32x4 acc[6];
#pragma unroll
    for (int j = 0; j < 6; ++j) acc[j] = (f32x4){0,0,0,0};
    const unsigned short* arow = &xsb[lrow*104 + kg*8];
#pragma unroll
    for (int kk = 0; kk < 3; ++kk){
        bf16x8 af = *(const bf16x8*)(arow + kk*32);
#pragma unroll
        for (int j = 0; j < 6; ++j){
            int col = nc0 + j*16 + lrow;
            bf16x8 bfr = *(const bf16x8*)(winb + (long)col*DM + kg*8 + kk*32);
            acc[j] = __builtin_amdgcn_mfma_f32_16x16x32_bf16(af, bfr, acc[j], 0,0,0);
        }
    }
    // C/D: col = l&15 (output col), row = kg*4 + reg (row-local)
#pragma unroll
    for (int j = 0; j < 6; ++j){
        int col = nc0 + j*16 + lrow;
#pragma unroll
        for (int reg = 0; reg < 4; ++reg){
            int row = r0 + kg*4 + reg;
            float v = acc[j][reg];
            if (col < DI) xin[(long)row*DI + col] = v;
            else          z[(long)row*DI + (col - DI)] = v;
        }
    }
}

// ---- 2. depthwise 3x3 conv + bias + SiLU, float4 channels ----
__global__ __launch_bounds__(256) void k_conv(const float* __restrict__ xin, const float* __restrict__ cwT,
                                              const float* __restrict__ cb, float* __restrict__ xc){
    int g = blockIdx.x * 256 + threadIdx.x;   // < BB*LL*48
    int dq = g % 48; int d0 = dq * 4;
    int l = (g / 48) % LL;
    int b = g / (48 * LL);
    int h = l >> 6, wwi = l & 63;
    float4 acc = *(const float4*)(cb + d0);
    const float* base = xin + (long)b * LL * DI + d0;
#pragma unroll
    for (int dy = 0; dy < 3; ++dy){
        int hh = h + dy - 1;
        if (hh < 0 || hh >= 64) continue;
#pragma unroll
        for (int dx = 0; dx < 3; ++dx){
            int wx = wwi + dx - 1;
            if (wx < 0 || wx >= 64) continue;
            float4 xv = *(const float4*)(base + (long)(hh*64 + wx)*DI);
            float4 wv = *(const float4*)(cwT + (dy*3 + dx)*DI + d0);
            acc.x += xv.x*wv.x; acc.y += xv.y*wv.y; acc.z += xv.z*wv.z; acc.w += xv.w*wv.w;
        }
    }
    float4 o;
    o.x = silu(acc.x); o.y = silu(acc.y); o.z = silu(acc.z); o.w = silu(acc.w);
    *(float4*)(xc + ((long)b*LL + l)*DI + d0) = o;
}

// ---- 3. x_proj + dt_proj + softplus — bf16 MFMA GEMM ----
#define XP 200
__global__ __launch_bounds__(256) void k_xdbl(const float* __restrict__ xc, const float* __restrict__ xpw,
                                              const float* __restrict__ dtw, const float* __restrict__ dtb,
                                              float* __restrict__ delta, float* __restrict__ bc2){
    __shared__ unsigned short xsb[64*XP];
    __shared__ unsigned short wsb[48*XP];
    __shared__ float ccs[64][40];
    __shared__ float dtws[DI*RR];
    int tid = threadIdx.x;
    int bk   = blockIdx.x >> 6;
    int tile = blockIdx.x & 63;
    int b = bk >> 2, k = bk & 3;
    int t0 = tile * 64;

    const float* wg = xpw + (long)k * C38 * DI;
    for (int i = tid; i < 48*DI; i += 256){
        int c = i / DI, d = i - c*DI;
        wsb[c*XP + d] = (c < C38) ? f2bf(wg[c*DI + d]) : (unsigned short)0;
    }
    const float* dg = dtw + (long)k * DI * RR;
    for (int i = tid; i < DI*RR; i += 256) dtws[i] = dg[i];
    for (int i = tid; i < 64*DI; i += 256){
        int r = i / DI, d = i - r*DI;
        int p = pos_of(k, t0 + r);
        xsb[r*XP + d] = f2bf(xc[((long)b*LL + p)*DI + d]);
    }
    __syncthreads();

    int wv = tid >> 6, l = tid & 63;
    int lrow = l & 15, kgrp = l >> 4;
    f32x4 acc0 = {0,0,0,0}, acc1 = {0,0,0,0}, acc2 = {0,0,0,0};
    const unsigned short* xrow = &xsb[(wv*16 + lrow)*XP + kgrp*8];
    const unsigned short* wrow = &wsb[lrow*XP + kgrp*8];
#pragma unroll
    for (int kk = 0; kk < 6; ++kk){
        bf16x8 af = *(const bf16x8*)(xrow + kk*32);
        bf16x8 b0 = *(const bf16x8*)(wrow + kk*32);
        bf16x8 b1 = *(const bf16x8*)(wrow + 16*XP + kk*32);
        bf16x8 b2 = *(const bf16x8*)(wrow + 32*XP + kk*32);
        acc0 = __builtin_amdgcn_mfma_f32_16x16x32_bf16(af, b0, acc0, 0,0,0);
        acc1 = __builtin_amdgcn_mfma_f32_16x16x32_bf16(af, b1, acc1, 0,0,0);
        acc2 = __builtin_amdgcn_mfma_f32_16x16x32_bf16(af, b2, acc2, 0,0,0);
    }
#pragma unroll
    for (int reg = 0; reg < 4; ++reg){
        int tl = wv*16 + kgrp*4 + reg;
        ccs[tl][lrow] = acc0[reg];
        ccs[tl][16 + lrow] = acc1[reg];
        if (lrow < 6) ccs[tl][32 + lrow] = acc2[reg];
    }
    __syncthreads();

    long obase = (long)bk * LL + t0;
    for (int i = tid; i < 64*DI; i += 256){
        int r = i / DI, d = i - r*DI;
        float raw = dtb[k*DI + d];
#pragma unroll
        for (int rr = 0; rr < RR; ++rr) raw += ccs[r][rr] * dtws[d*RR + rr];
        float sp = (raw > 15.f) ? raw : __logf(1.f + __expf(raw));
        delta[(obase + r)*DI + d] = sp;
    }
    for (int i = tid; i < 64*32; i += 256){
        int r = i >> 5, q = i & 31;
        bc2[(obase + r)*32 + q] = ccs[r][6 + q];
    }
}

// ---- 4. scan pass A: per-chunk local end-state + delta-sum ----
__global__ __launch_bounds__(192) void k_scanA(const float* __restrict__ delta, const float* __restrict__ bc2,
                                               const float* __restrict__ xc, const float* __restrict__ alog,
                                               float* __restrict__ hloc, float* __restrict__ Ssum){
    int tid = threadIdx.x;
    int j = tid & 1, dl = tid >> 1;
    int bid = blockIdx.x;
    int dg = bid & 1; int c = (bid >> 1) & 63; int bk = bid >> 7;
    int b = bk >> 2, k = bk & 3;
    int d = dg*96 + dl;
    int n0 = j*8;
    float a[8]; bool fast = true;
#pragma unroll
    for (int n = 0; n < 8; ++n){
        a[n] = -__expf(alog[(k*DI + d)*NS + n0 + n]);
        fast = fast && (fabsf(a[n] + (float)(n0 + n + 1)) < 1e-4f*(float)(n0 + n + 1));
    }
    int t0 = c * CL;
    int p0, st;
    if (k == 0){ p0 = t0;         st = 1;   }
    else if (k == 1){ p0 = c;     st = 64;  }
    else if (k == 2){ p0 = LL-1-t0; st = -1;  }
    else            { p0 = LL-1-c;  st = -64; }
    const float* dep = delta + ((long)bk*LL + t0)*DI + d;
    const float* bcp = bc2   + ((long)bk*LL + t0)*32 + n0;
    const float* up  = xc + ((long)b*LL + p0)*DI + d;
    long ustep = (long)st * DI;
    float h[8] = {0,0,0,0,0,0,0,0};
    float S = 0.f;
    if (fast){
#pragma unroll 4
        for (int i = 0; i < CL; ++i){
            float de = *dep;
            float u  = *up;
            float4 bv0 = *(const float4*)(bcp);
            float4 bv1 = *(const float4*)(bcp + 4);
            float E  = __expf(-de);
            float E2 = E*E, E3 = E2*E, E4 = E2*E2;
            float E5 = E4*E, E6 = E4*E2, E7 = E4*E3, E8 = E4*E4;
            float s8 = j ? E8 : 1.f;
            float p1=E*s8, p2=E2*s8, p3=E3*s8, p4=E4*s8, p5=E5*s8, p6=E6*s8, p7=E7*s8, p8=E8*s8;
            float du = de * u;
            S += de;
            h[0] = h[0]*p1 + du*bv0.x;  h[1] = h[1]*p2 + du*bv0.y;
            h[2] = h[2]*p3 + du*bv0.z;  h[3] = h[3]*p4 + du*bv0.w;
            h[4] = h[4]*p5 + du*bv1.x;  h[5] = h[5]*p6 + du*bv1.y;
            h[6] = h[6]*p7 + du*bv1.z;  h[7] = h[7]*p8 + du*bv1.w;
            dep += DI; up += ustep; bcp += 32;
        }
    } else {
        for (int i = 0; i < CL; ++i){
            float de = *dep;
            float u  = *up;
            float4 bv0 = *(const float4*)(bcp);
            float4 bv1 = *(const float4*)(bcp + 4);
            float du = de * u;
            S += de;
            float bb[8] = {bv0.x,bv0.y,bv0.z,bv0.w,bv1.x,bv1.y,bv1.z,bv1.w};
#pragma unroll
            for (int n = 0; n < 8; ++n){ float dA = __expf(de*a[n]); h[n] = h[n]*dA + du*bb[n]; }
            dep += DI; up += ustep; bcp += 32;
        }
    }
    long ho = (((long)bk*NC + c)*DI + d)*NS + n0;
    *(float4*)(hloc + ho)     = make_float4(h[0],h[1],h[2],h[3]);
    *(float4*)(hloc + ho + 4) = make_float4(h[4],h[5],h[6],h[7]);
    if (j == 0) Ssum[((long)bk*NC + c)*DI + d] = S;
}

// ---- 5. scan pass B ----
__global__ __launch_bounds__(256) void k_scanB(float* __restrict__ hloc, const float* __restrict__ Ssum,
                                               const float* __restrict__ alog){
    int gid = blockIdx.x * 256 + threadIdx.x;
    int dn = gid % (DI*NS);
    int bk = gid / (DI*NS);
    int d = dn >> 4, n = dn & 15;
    int k = bk & 3;
    float a = -__expf(alog[(k*DI + d)*NS + n]);
    float h = 0.f;
    long base  = (long)bk * NC * DI * NS + dn;
    long sbase = (long)bk * NC * DI + d;
#pragma unroll 4
    for (int c = 0; c < NC; ++c){
        long o = base + (long)c * DI * NS;
        float P = __expf(a * Ssum[sbase + (long)c * DI]);
        float tmp = hloc[o];
        hloc[o] = h;
        h = h * P + tmp;
    }
}

// ---- 6. scan pass C: replay, emit y at SPATIAL position ----
__global__ __launch_bounds__(192) void k_scanC(const float* __restrict__ delta, const float* __restrict__ bc2,
                                               const float* __restrict__ xc, const float* __restrict__ alog,
                                               const float* __restrict__ hloc, float* __restrict__ ys){
    int tid = threadIdx.x;
    int j = tid & 1, dl = tid >> 1;
    int bid = blockIdx.x;
    int dg = bid & 1; int c = (bid >> 1) & 63; int bk = bid >> 7;
    int b = bk >> 2, k = bk & 3;
    int d = dg*96 + dl;
    int n0 = j*8;
    float a[8]; bool fast = true;
#pragma unroll
    for (int n = 0; n < 8; ++n){
        a[n] = -__expf(alog[(k*DI + d)*NS + n0 + n]);
        fast = fast && (fabsf(a[n] + (float)(n0 + n + 1)) < 1e-4f*(float)(n0 + n + 1));
    }
    int t0 = c * CL;
    int p0, st;
    if (k == 0){ p0 = t0;         st = 1;   }
    else if (k == 1){ p0 = c;     st = 64;  }
    else if (k == 2){ p0 = LL-1-t0; st = -1;  }
    else            { p0 = LL-1-c;  st = -64; }
    const float* dep = delta + ((long)bk*LL + t0)*DI + d;
    const float* bcp = bc2   + ((long)bk*LL + t0)*32 + n0;
    const float* up  = xc + ((long)b*LL + p0)*DI + d;
    float*       yp  = ys + ((long)bk*LL + p0)*DI + d;
    long ustep = (long)st * DI;
    long ho = (((long)bk*NC + c)*DI + d)*NS + n0;
    float4 h03 = *(const float4*)(hloc + ho);
    float4 h47 = *(const float4*)(hloc + ho + 4);
    float h[8] = {h03.x,h03.y,h03.z,h03.w,h47.x,h47.y,h47.z,h47.w};
    if (fast){
#pragma unroll 4
        for (int i = 0; i < CL; ++i){
            float de = *dep;
            float u  = *up;
            float4 bv0 = *(const float4*)(bcp);
            float4 bv1 = *(const float4*)(bcp + 4);
            float4 cv0 = *(const float4*)(bcp + 16);
            float4 cv1 = *(const float4*)(bcp + 20);
            float E  = __expf(-de);
            float E2 = E*E, E3 = E2*E, E4 = E2*E2;
            float E5 = E4*E, E6 = E4*E2, E7 = E4*E3, E8 = E4*E4;
            float s8 = j ? E8 : 1.f;
            float p1=E*s8, p2=E2*s8, p3=E3*s8, p4=E4*s8, p5=E5*s8, p6=E6*s8, p7=E7*s8, p8=E8*s8;
            float du = de * u;
            h[0] = h[0]*p1 + du*bv0.x;  h[1] = h[1]*p2 + du*bv0.y;
            h[2] = h[2]*p3 + du*bv0.z;  h[3] = h[3]*p4 + du*bv0.w;
            h[4] = h[4]*p5 + du*bv1.x;  h[5] = h[5]*p6 + du*bv1.y;
            h[6] = h[6]*p7 + du*bv1.z;  h[7] = h[7]*p8 + du*bv1.w;
            float y = h[0]*cv0.x + h[1]*cv0.y + h[2]*cv0.z + h[3]*cv0.w
                    + h[4]*cv1.x + h[5]*cv1.y + h[6]*cv1.z + h[7]*cv1.w;
            y += __shfl_xor(y, 1, 64);
            if (j == 0) *yp = y;
            dep += DI; up += ustep; yp += ustep; bcp += 32;
        }
    } else {
        for (int i = 0; i < CL; ++i){
            float de = *dep;
            float u  = *up;
            float4 bv0 = *(const float4*)(bcp);
            float4 bv1 = *(const float4*)(bcp + 4);
            float4 cv0 = *(const float4*)(bcp + 16);
            float4 cv1 = *(const float4*)(bcp + 20);
            float du = de * u;
            float bb[8] = {bv0.x,bv0.y,bv0.z,bv0.w,bv1.x,bv1.y,bv1.z,bv1.w};
            float cc[8] = {cv0.x,cv0.y,cv0.z,cv0.w,cv1.x,cv1.y,cv1.z,cv1.w};
            float y = 0.f;
#pragma unroll
            for (int n = 0; n < 8; ++n){ float dA = __expf(de*a[n]); h[n] = h[n]*dA + du*bb[n]; y += h[n]*cc[n]; }
            y += __shfl_xor(y, 1, 64);
            if (j == 0) *yp = y;
            dep += DI; up += ustep; yp += ustep; bcp += 32;
        }
    }
}

// ---- 7. merge + LN + gate + out_proj ----
__global__ __launch_bounds__(192) void k_fuse(const float* __restrict__ ys, const float* __restrict__ xc,
                                              const float* __restrict__ z, const float* __restrict__ Dsk,
                                              const float* __restrict__ lnw, const float* __restrict__ lnb,
                                              const float* __restrict__ wout, float* __restrict__ out){
    __shared__ float yv[4][DI];
    __shared__ float red[2][3];
    __shared__ float part[2][4][96];
    int tid = threadIdx.x;
    int b  = blockIdx.x / (LL/4);
    int p0 = (blockIdx.x % (LL/4)) * 4;
    int d = tid;
    float sumD = Dsk[d] + Dsk[DI + d] + Dsk[2*DI + d] + Dsk[3*DI + d];
    float lw = lnw[d], lb = lnb[d];
    for (int pp = 0; pp < 4; ++pp){
        int p = p0 + pp;
        long yb = ((long)b*4)*LL*DI + (long)p*DI + d;
        float y = ys[yb] + ys[yb + (long)LL*DI] + ys[yb + 2L*LL*DI] + ys[yb + 3L*LL*DI];
        y += xc[((long)b*LL + p)*DI + d] * sumD;
        float s = y, sq = y*y;
#pragma unroll
        for (int m = 32; m > 0; m >>= 1){ s += __shfl_down(s, m, 64); sq += __shfl_down(sq, m, 64); }
        int wvi = tid >> 6, ln = tid & 63;
        if (ln == 0){ red[0][wvi] = s; red[1][wvi] = sq; }
        __syncthreads();
        float st  = red[0][0] + red[0][1] + red[0][2];
        float sqt = red[1][0] + red[1][1] + red[1][2];
        float mu  = st / DI;
        float var = sqt / DI - mu*mu;
        float rs  = rsqrtf(var + 1e-5f);
        float yn  = (y - mu)*rs*lw + lb;
        float zg  = z[((long)b*LL + p)*DI + d];
        yv[pp][d] = yn * silu(zg);
        __syncthreads();
    }
    int m = tid % 96, half = tid / 96;
    float acc[4] = {0.f, 0.f, 0.f, 0.f};
    const float* wr = wout + (long)m*DI + half*96;
    for (int dd = 0; dd < 96; ++dd){
        float wv = wr[dd];
        int df = half*96 + dd;
#pragma unroll
        for (int pp = 0; pp < 4; ++pp) acc[pp] += wv * yv[pp][df];
    }
#pragma unroll
    for (int pp = 0; pp < 4; ++pp) part[half][pp][m] = acc[pp];
    __syncthreads();
    if (tid < 96){
#pragma unroll
        for (int pp = 0; pp < 4; ++pp){
            float v = part[0][pp][tid] + part[1][pp][tid];
            out[((long)b*LL + p0 + pp)*DM + tid] = v;
        }
    }
}

extern "C" void kernel_launch(void* const* d_in, const int* in_sizes, int n_in,
                              void* d_out, int out_size, void* d_ws, size_t ws_size,
                              hipStream_t stream){
    (void)in_sizes; (void)n_in; (void)out_size; (void)ws_size;
    const float* x    = (const float*)d_in[0];
    const float* win  = (const float*)d_in[1];
    const float* cw   = (const float*)d_in[2];
    const float* cb   = (const float*)d_in[3];
    const float* xpw  = (const float*)d_in[4];
    const float* dtw  = (const float*)d_in[5];
    const float* dtb  = (const float*)d_in[6];
    const float* alog = (const float*)d_in[7];
    const float* ds   = (const float*)d_in[8];
    const float* lnw  = (const float*)d_in[9];
    const float* lnb  = (const float*)d_in[10];
    const float* wout = (const float*)d_in[11];

    float* ws    = (float*)d_ws;
    float* xin   = ws + OFF_XIN;
    float* z     = ws + OFF_Z;
    float* xc    = ws + OFF_XC;
    float* delta = ws + OFF_DELTA;
    float* bc2   = ws + OFF_BC;
    float* ysb   = ws + OFF_YS;
    float* Ssum  = ws + OFF_S;
    unsigned short* winb = (unsigned short*)(ws + OFF_WB);
    float* cwT   = ws + OFF_CWT;
    float* hloc  = ws + OFF_HLOC;

    k_prep  <<<dim3(144),  dim3(256), 0, stream>>>(win, cw, winb, cwT);
    k_inproj<<<dim3(1024), dim3(256), 0, stream>>>(x, winb, xin, z);
    k_conv  <<<dim3(3072), dim3(256), 0, stream>>>(xin, cwT, cb, xc);
    k_xdbl  <<<dim3(1024), dim3(256), 0, stream>>>(xc, xpw, dtw, dtb, delta, bc2);
    k_scanA <<<dim3(2048), dim3(192), 0, stream>>>(delta, bc2, xc, alog, hloc, Ssum);
    k_scanB <<<dim3(192),  dim3(256), 0, stream>>>(hloc, Ssum, alog);
    k_scanC <<<dim3(2048), dim3(192), 0, stream>>>(delta, bc2, xc, alog, hloc, ysb);
    k_fuse  <<<dim3(4096), dim3(192), 0, stream>>>(ysb, xc, z, ds, lnw, lnb, wout,
                                                   (float*)d_out);
}

// Round 8
// 257.656 us; speedup vs baseline: 1.2060x; 1.0077x over previous
//
#include <hip/hip_runtime.h>
#include <hip/hip_bf16.h>

#define DEV static __device__ __forceinline__

DEV float silu(float x){ return x / (1.f + __expf(-x)); }

typedef __attribute__((ext_vector_type(8))) short bf16x8;
typedef __attribute__((ext_vector_type(4))) float f32x4;

DEV unsigned short f2bf(float f){
    unsigned u = __float_as_uint(f);
    u += 0x7FFF + ((u >> 16) & 1);      // RNE
    return (unsigned short)(u >> 16);
}

// ---- problem sizes ----
#define BB 4
#define LL 4096          // H*W, H=W=64
#define DM 96
#define DI 192
#define NS 16
#define KK 4
#define RR 6
#define C38 38
#define NC 64            // chunks
#define CL 64            // chunk length

// ---- workspace layout (float offsets) ----
#define OFF_XIN   0
#define OFF_Z     (OFF_XIN + BB*LL*DI)
#define OFF_XC    (OFF_Z + BB*LL*DI)
#define OFF_DELTA (OFF_XC + BB*LL*DI)
#define OFF_BC    (OFF_DELTA + BB*KK*LL*DI)
#define OFF_YS    (OFF_BC + BB*KK*LL*32)
#define OFF_S     (OFF_YS + BB*KK*LL*DI)
#define OFF_WB    (OFF_S + BB*KK*NC*DI)     // bf16 in_proj weights
#define OFF_CWT   (OFF_WB + 18432)          // transposed conv weights
#define OFF_HLOC  OFF_XIN   // hloc aliases XIN (dead after k_conv)

DEV int pos_of(int k, int t){
    int pr = ((t & 63) << 6) | (t >> 6);
    int p  = (k & 1) ? pr : t;
    if (k & 2) p = LL - 1 - p;
    return p;
}

// ---- 0. prep ----
__global__ __launch_bounds__(256) void k_prep(const float* __restrict__ win, const float* __restrict__ cw,
                                              unsigned short* __restrict__ winb, float* __restrict__ cwT){
    int i = blockIdx.x * 256 + threadIdx.x;
    if (i < 384*DM) winb[i] = f2bf(win[i]);
    if (i < 9*DI){ int tap = i / DI, d = i - tap*DI; cwT[i] = cw[d*9 + tap]; }
}

// ---- 1. in_proj: bf16 MFMA GEMM ----
__global__ __launch_bounds__(256) void k_inproj(const float* __restrict__ x, const unsigned short* __restrict__ winb,
                                                float* __restrict__ xin, float* __restrict__ z){
    __shared__ unsigned short xsb[16*104];
    int tid = threadIdx.x;
    int r0 = blockIdx.x * 16;
    const float* xrow = x + (long)r0 * DM;
    for (int i = tid; i < 16*DM; i += 256){
        int r = i / DM, d = i - r*DM;
        xsb[r*104 + d] = f2bf(xrow[i]);
    }
    __syncthreads();
    int wv = tid >> 6, l = tid & 63;
    int lrow = l & 15, kg = l >> 4;
    int nc0 = wv * 96;
    f32x4 acc[6];
#pragma unroll
    for (int j = 0; j < 6; ++j) acc[j] = (f32x4){0,0,0,0};
    const unsigned short* arow = &xsb[lrow*104 + kg*8];
#pragma unroll
    for (int kk = 0; kk < 3; ++kk){
        bf16x8 af = *(const bf16x8*)(arow + kk*32);
#pragma unroll
        for (int j = 0; j < 6; ++j){
            int col = nc0 + j*16 + lrow;
            bf16x8 bfr = *(const bf16x8*)(winb + (long)col*DM + kg*8 + kk*32);
            acc[j] = __builtin_amdgcn_mfma_f32_16x16x32_bf16(af, bfr, acc[j], 0,0,0);
        }
    }
#pragma unroll
    for (int j = 0; j < 6; ++j){
        int col = nc0 + j*16 + lrow;
#pragma unroll
        for (int reg = 0; reg < 4; ++reg){
            int row = r0 + kg*4 + reg;
            float v = acc[j][reg];
            if (col < DI) xin[(long)row*DI + col] = v;
            else          z[(long)row*DI + (col - DI)] = v;
        }
    }
}

// ---- 2. depthwise conv + SiLU, float4 ----
__global__ __launch_bounds__(256) void k_conv(const float* __restrict__ xin, const float* __restrict__ cwT,
                                              const float* __restrict__ cb, float* __restrict__ xc){
    int g = blockIdx.x * 256 + threadIdx.x;
    int dq = g % 48; int d0 = dq * 4;
    int l = (g / 48) % LL;
    int b = g / (48 * LL);
    int h = l >> 6, wwi = l & 63;
    float4 acc = *(const float4*)(cb + d0);
    const float* base = xin + (long)b * LL * DI + d0;
#pragma unroll
    for (int dy = 0; dy < 3; ++dy){
        int hh = h + dy - 1;
        if (hh < 0 || hh >= 64) continue;
#pragma unroll
        for (int dx = 0; dx < 3; ++dx){
            int wx = wwi + dx - 1;
            if (wx < 0 || wx >= 64) continue;
            float4 xv = *(const float4*)(base + (long)(hh*64 + wx)*DI);
            float4 wv = *(const float4*)(cwT + (dy*3 + dx)*DI + d0);
            acc.x += xv.x*wv.x; acc.y += xv.y*wv.y; acc.z += xv.z*wv.z; acc.w += xv.w*wv.w;
        }
    }
    float4 o;
    o.x = silu(acc.x); o.y = silu(acc.y); o.z = silu(acc.z); o.w = silu(acc.w);
    *(float4*)(xc + ((long)b*LL + l)*DI + d0) = o;
}

// ---- 3. x_proj + dt_proj + softplus — bf16 MFMA GEMM ----
#define XP 200
__global__ __launch_bounds__(256) void k_xdbl(const float* __restrict__ xc, const float* __restrict__ xpw,
                                              const float* __restrict__ dtw, const float* __restrict__ dtb,
                                              float* __restrict__ delta, float* __restrict__ bc2){
    __shared__ unsigned short xsb[64*XP];
    __shared__ unsigned short wsb[48*XP];
    __shared__ float ccs[64][40];
    __shared__ float dtws[DI*RR];
    int tid = threadIdx.x;
    int bk   = blockIdx.x >> 6;
    int tile = blockIdx.x & 63;
    int b = bk >> 2, k = bk & 3;
    int t0 = tile * 64;

    const float* wg = xpw + (long)k * C38 * DI;
    for (int i = tid; i < 48*DI; i += 256){
        int c = i / DI, d = i - c*DI;
        wsb[c*XP + d] = (c < C38) ? f2bf(wg[c*DI + d]) : (unsigned short)0;
    }
    const float* dg = dtw + (long)k * DI * RR;
    for (int i = tid; i < DI*RR; i += 256) dtws[i] = dg[i];
    for (int i = tid; i < 64*DI; i += 256){
        int r = i / DI, d = i - r*DI;
        int p = pos_of(k, t0 + r);
        xsb[r*XP + d] = f2bf(xc[((long)b*LL + p)*DI + d]);
    }
    __syncthreads();

    int wv = tid >> 6, l = tid & 63;
    int lrow = l & 15, kgrp = l >> 4;
    f32x4 acc0 = {0,0,0,0}, acc1 = {0,0,0,0}, acc2 = {0,0,0,0};
    const unsigned short* xrow = &xsb[(wv*16 + lrow)*XP + kgrp*8];
    const unsigned short* wrow = &wsb[lrow*XP + kgrp*8];
#pragma unroll
    for (int kk = 0; kk < 6; ++kk){
        bf16x8 af = *(const bf16x8*)(xrow + kk*32);
        bf16x8 b0 = *(const bf16x8*)(wrow + kk*32);
        bf16x8 b1 = *(const bf16x8*)(wrow + 16*XP + kk*32);
        bf16x8 b2 = *(const bf16x8*)(wrow + 32*XP + kk*32);
        acc0 = __builtin_amdgcn_mfma_f32_16x16x32_bf16(af, b0, acc0, 0,0,0);
        acc1 = __builtin_amdgcn_mfma_f32_16x16x32_bf16(af, b1, acc1, 0,0,0);
        acc2 = __builtin_amdgcn_mfma_f32_16x16x32_bf16(af, b2, acc2, 0,0,0);
    }
#pragma unroll
    for (int reg = 0; reg < 4; ++reg){
        int tl = wv*16 + kgrp*4 + reg;
        ccs[tl][lrow] = acc0[reg];
        ccs[tl][16 + lrow] = acc1[reg];
        if (lrow < 6) ccs[tl][32 + lrow] = acc2[reg];
    }
    __syncthreads();

    long obase = (long)bk * LL + t0;
    for (int i = tid; i < 64*DI; i += 256){
        int r = i / DI, d = i - r*DI;
        float raw = dtb[k*DI + d];
#pragma unroll
        for (int rr = 0; rr < RR; ++rr) raw += ccs[r][rr] * dtws[d*RR + rr];
        float sp = (raw > 15.f) ? raw : __logf(1.f + __expf(raw));
        delta[(obase + r)*DI + d] = sp;
    }
    for (int i = tid; i < 64*32; i += 256){
        int r = i >> 5, q = i & 31;
        bc2[(obase + r)*32 + q] = ccs[r][6 + q];
    }
}

// ---- 4. scan pass A: 256 thr = 64 d x 4 j (4 n-states each); depth-2 pipelined ----
__global__ __launch_bounds__(256) void k_scanA(const float* __restrict__ delta, const float* __restrict__ bc2,
                                               const float* __restrict__ xc, const float* __restrict__ alog,
                                               float* __restrict__ hloc, float* __restrict__ Ssum){
    int tid = threadIdx.x;
    int j = tid & 3, dl = tid >> 2;
    int bid = blockIdx.x;
    int dgp = bid % 3; int rest = bid / 3;
    int c = rest & 63; int bk = rest >> 6;
    int b = bk >> 2, k = bk & 3;
    int d = dgp*64 + dl;
    int n0 = j*4;
    float a[4]; bool fast = true;
#pragma unroll
    for (int n = 0; n < 4; ++n){
        a[n] = -__expf(alog[(k*DI + d)*NS + n0 + n]);
        fast = fast && (fabsf(a[n] + (float)(n0 + n + 1)) < 1e-4f*(float)(n0 + n + 1));
    }
    int t0 = c * CL;
    int p0, st;
    if (k == 0){ p0 = t0;         st = 1;   }
    else if (k == 1){ p0 = c;     st = 64;  }
    else if (k == 2){ p0 = LL-1-t0; st = -1;  }
    else            { p0 = LL-1-c;  st = -64; }
    const float* dep = delta + ((long)bk*LL + t0)*DI + d;
    const float* bcp = bc2   + ((long)bk*LL + t0)*32 + n0;
    const float* up  = xc + ((long)b*LL + p0)*DI + d;
    long ustep = (long)st * DI;
    float h0=0.f, h1=0.f, h2=0.f, h3=0.f;
    float S = 0.f;
    if (fast){
        float de = *dep, u = *up;
        float4 bv = *(const float4*)bcp;
        for (int i = 0; i < CL; ++i){
            dep += DI; up += ustep; bcp += 32;
            float de_n = *dep;                       // prefetch next (tail over-read stays in ws)
            float u_n  = *up;
            float4 bv_n = *(const float4*)bcp;
            float E  = __expf(-de);
            float E2 = E*E, E3 = E2*E, E4 = E2*E2;
            float sj = 1.f;
            if (j & 1) sj = E4;
            if (j & 2) sj *= E4*E4;
            float du = de * u;
            S += de;
            h0 = h0*(E *sj) + du*bv.x;
            h1 = h1*(E2*sj) + du*bv.y;
            h2 = h2*(E3*sj) + du*bv.z;
            h3 = h3*(E4*sj) + du*bv.w;
            de = de_n; u = u_n; bv = bv_n;
        }
    } else {
        for (int i = 0; i < CL; ++i){
            float de = *dep;
            float u  = *up;
            float4 bv = *(const float4*)bcp;
            float du = de * u;
            S += de;
            float dA0 = __expf(de*a[0]), dA1 = __expf(de*a[1]);
            float dA2 = __expf(de*a[2]), dA3 = __expf(de*a[3]);
            h0 = h0*dA0 + du*bv.x; h1 = h1*dA1 + du*bv.y;
            h2 = h2*dA2 + du*bv.z; h3 = h3*dA3 + du*bv.w;
            dep += DI; up += ustep; bcp += 32;
        }
    }
    long ho = (((long)bk*NC + c)*DI + d)*NS + n0;
    *(float4*)(hloc + ho) = make_float4(h0,h1,h2,h3);
    if (j == 0) Ssum[((long)bk*NC + c)*DI + d] = S;
}

// ---- 5. scan pass B: chunk combine, prefetched ----
__global__ __launch_bounds__(256) void k_scanB(float* __restrict__ hloc, const float* __restrict__ Ssum,
                                               const float* __restrict__ alog){
    int gid = blockIdx.x * 256 + threadIdx.x;
    int dn = gid % (DI*NS);
    int bk = gid / (DI*NS);
    int d = dn >> 4, n = dn & 15;
    int k = bk & 3;
    float a = -__expf(alog[(k*DI + d)*NS + n]);
    float h = 0.f;
    long o     = (long)bk * NC * DI * NS + dn;
    long sbase = (long)bk * NC * DI + d;
    float Sc  = Ssum[sbase];
    float tmp = hloc[o];
    for (int c = 0; c < NC; ++c){
        long o_n = o + (long)DI*NS;
        float Sc_n  = Ssum[sbase + (long)(c+1)*DI];   // tail over-read stays in ws
        float tmp_n = hloc[o_n];
        float P = __expf(a * Sc);
        hloc[o] = h;
        h = h * P + tmp;
        o = o_n; Sc = Sc_n; tmp = tmp_n;
    }
}

// ---- 6. scan pass C: 256 thr = 64 d x 4 j; depth-2 pipelined; y at SPATIAL position ----
__global__ __launch_bounds__(256) void k_scanC(const float* __restrict__ delta, const float* __restrict__ bc2,
                                               const float* __restrict__ xc, const float* __restrict__ alog,
                                               const float* __restrict__ hloc, float* __restrict__ ys){
    int tid = threadIdx.x;
    int j = tid & 3, dl = tid >> 2;
    int bid = blockIdx.x;
    int dgp = bid % 3; int rest = bid / 3;
    int c = rest & 63; int bk = rest >> 6;
    int b = bk >> 2, k = bk & 3;
    int d = dgp*64 + dl;
    int n0 = j*4;
    float a[4]; bool fast = true;
#pragma unroll
    for (int n = 0; n < 4; ++n){
        a[n] = -__expf(alog[(k*DI + d)*NS + n0 + n]);
        fast = fast && (fabsf(a[n] + (float)(n0 + n + 1)) < 1e-4f*(float)(n0 + n + 1));
    }
    int t0 = c * CL;
    int p0, st;
    if (k == 0){ p0 = t0;         st = 1;   }
    else if (k == 1){ p0 = c;     st = 64;  }
    else if (k == 2){ p0 = LL-1-t0; st = -1;  }
    else            { p0 = LL-1-c;  st = -64; }
    const float* dep = delta + ((long)bk*LL + t0)*DI + d;
    const float* bcp = bc2   + ((long)bk*LL + t0)*32 + n0;
    const float* up  = xc + ((long)b*LL + p0)*DI + d;
    float*       yp  = ys + ((long)bk*LL + p0)*DI + d;
    long ustep = (long)st * DI;
    long ho = (((long)bk*NC + c)*DI + d)*NS + n0;
    float4 hv = *(const float4*)(hloc + ho);
    float h0 = hv.x, h1 = hv.y, h2 = hv.z, h3 = hv.w;
    if (fast){
        float de = *dep, u = *up;
        float4 bv = *(const float4*)bcp;
        float4 cv = *(const float4*)(bcp + 16);
        for (int i = 0; i < CL; ++i){
            dep += DI; up += ustep; bcp += 32;
            float de_n = *dep;
            float u_n  = *up;
            float4 bv_n = *(const float4*)bcp;
            float4 cv_n = *(const float4*)(bcp + 16);
            float E  = __expf(-de);
            float E2 = E*E, E3 = E2*E, E4 = E2*E2;
            float sj = 1.f;
            if (j & 1) sj = E4;
            if (j & 2) sj *= E4*E4;
            float du = de * u;
            h0 = h0*(E *sj) + du*bv.x;
            h1 = h1*(E2*sj) + du*bv.y;
            h2 = h2*(E3*sj) + du*bv.z;
            h3 = h3*(E4*sj) + du*bv.w;
            float y = h0*cv.x + h1*cv.y + h2*cv.z + h3*cv.w;
            y += __shfl_xor(y, 1, 64);
            y += __shfl_xor(y, 2, 64);
            if (j == 0) *yp = y;
            yp += ustep;
            de = de_n; u = u_n; bv = bv_n; cv = cv_n;
        }
    } else {
        for (int i = 0; i < CL; ++i){
            float de = *dep;
            float u  = *up;
            float4 bv = *(const float4*)bcp;
            float4 cv = *(const float4*)(bcp + 16);
            float du = de * u;
            float dA0 = __expf(de*a[0]), dA1 = __expf(de*a[1]);
            float dA2 = __expf(de*a[2]), dA3 = __expf(de*a[3]);
            h0 = h0*dA0 + du*bv.x; h1 = h1*dA1 + du*bv.y;
            h2 = h2*dA2 + du*bv.z; h3 = h3*dA3 + du*bv.w;
            float y = h0*cv.x + h1*cv.y + h2*cv.z + h3*cv.w;
            y += __shfl_xor(y, 1, 64);
            y += __shfl_xor(y, 2, 64);
            if (j == 0) *yp = y;
            dep += DI; up += ustep; yp += ustep; bcp += 32;
        }
    }
}

// ---- 7. merge + LN + gate + out_proj ----
__global__ __launch_bounds__(192) void k_fuse(const float* __restrict__ ys, const float* __restrict__ xc,
                                              const float* __restrict__ z, const float* __restrict__ Dsk,
                                              const float* __restrict__ lnw, const float* __restrict__ lnb,
                                              const float* __restrict__ wout, float* __restrict__ out){
    __shared__ float yv[4][DI];
    __shared__ float red[2][3];
    __shared__ float part[2][4][96];
    int tid = threadIdx.x;
    int b  = blockIdx.x / (LL/4);
    int p0 = (blockIdx.x % (LL/4)) * 4;
    int d = tid;
    float sumD = Dsk[d] + Dsk[DI + d] + Dsk[2*DI + d] + Dsk[3*DI + d];
    float lw = lnw[d], lb = lnb[d];
    for (int pp = 0; pp < 4; ++pp){
        int p = p0 + pp;
        long yb = ((long)b*4)*LL*DI + (long)p*DI + d;
        float y = ys[yb] + ys[yb + (long)LL*DI] + ys[yb + 2L*LL*DI] + ys[yb + 3L*LL*DI];
        y += xc[((long)b*LL + p)*DI + d] * sumD;
        float s = y, sq = y*y;
#pragma unroll
        for (int m = 32; m > 0; m >>= 1){ s += __shfl_down(s, m, 64); sq += __shfl_down(sq, m, 64); }
        int wvi = tid >> 6, ln = tid & 63;
        if (ln == 0){ red[0][wvi] = s; red[1][wvi] = sq; }
        __syncthreads();
        float st  = red[0][0] + red[0][1] + red[0][2];
        float sqt = red[1][0] + red[1][1] + red[1][2];
        float mu  = st / DI;
        float var = sqt / DI - mu*mu;
        float rs  = rsqrtf(var + 1e-5f);
        float yn  = (y - mu)*rs*lw + lb;
        float zg  = z[((long)b*LL + p)*DI + d];
        yv[pp][d] = yn * silu(zg);
        __syncthreads();
    }
    int m = tid % 96, half = tid / 96;
    float acc[4] = {0.f, 0.f, 0.f, 0.f};
    const float* wr = wout + (long)m*DI + half*96;
    for (int dd = 0; dd < 96; ++dd){
        float wv = wr[dd];
        int df = half*96 + dd;
#pragma unroll
        for (int pp = 0; pp < 4; ++pp) acc[pp] += wv * yv[pp][df];
    }
#pragma unroll
    for (int pp = 0; pp < 4; ++pp) part[half][pp][m] = acc[pp];
    __syncthreads();
    if (tid < 96){
#pragma unroll
        for (int pp = 0; pp < 4; ++pp){
            float v = part[0][pp][tid] + part[1][pp][tid];
            out[((long)b*LL + p0 + pp)*DM + tid] = v;
        }
    }
}

extern "C" void kernel_launch(void* const* d_in, const int* in_sizes, int n_in,
                              void* d_out, int out_size, void* d_ws, size_t ws_size,
                              hipStream_t stream){
    (void)in_sizes; (void)n_in; (void)out_size; (void)ws_size;
    const float* x    = (const float*)d_in[0];
    const float* win  = (const float*)d_in[1];
    const float* cw   = (const float*)d_in[2];
    const float* cb   = (const float*)d_in[3];
    const float* xpw  = (const float*)d_in[4];
    const float* dtw  = (const float*)d_in[5];
    const float* dtb  = (const float*)d_in[6];
    const float* alog = (const float*)d_in[7];
    const float* ds   = (const float*)d_in[8];
    const float* lnw  = (const float*)d_in[9];
    const float* lnb  = (const float*)d_in[10];
    const float* wout = (const float*)d_in[11];

    float* ws    = (float*)d_ws;
    float* xin   = ws + OFF_XIN;
    float* z     = ws + OFF_Z;
    float* xc    = ws + OFF_XC;
    float* delta = ws + OFF_DELTA;
    float* bc2   = ws + OFF_BC;
    float* ysb   = ws + OFF_YS;
    float* Ssum  = ws + OFF_S;
    unsigned short* winb = (unsigned short*)(ws + OFF_WB);
    float* cwT   = ws + OFF_CWT;
    float* hloc  = ws + OFF_HLOC;

    k_prep  <<<dim3(144),  dim3(256), 0, stream>>>(win, cw, winb, cwT);
    k_inproj<<<dim3(1024), dim3(256), 0, stream>>>(x, winb, xin, z);
    k_conv  <<<dim3(3072), dim3(256), 0, stream>>>(xin, cwT, cb, xc);
    k_xdbl  <<<dim3(1024), dim3(256), 0, stream>>>(xc, xpw, dtw, dtb, delta, bc2);
    k_scanA <<<dim3(3072), dim3(256), 0, stream>>>(delta, bc2, xc, alog, hloc, Ssum);
    k_scanB <<<dim3(192),  dim3(256), 0, stream>>>(hloc, Ssum, alog);
    k_scanC <<<dim3(3072), dim3(256), 0, stream>>>(delta, bc2, xc, alog, hloc, ysb);
    k_fuse  <<<dim3(4096), dim3(192), 0, stream>>>(ysb, xc, z, ds, lnw, lnb, wout,
                                                   (float*)d_out);
}

// Round 9
// 221.048 us; speedup vs baseline: 1.4057x; 1.1656x over previous
//
#include <hip/hip_runtime.h>
#include <hip/hip_bf16.h>

#define DEV static __device__ __forceinline__

DEV float silu(float x){ return x / (1.f + __expf(-x)); }

typedef __attribute__((ext_vector_type(8))) short bf16x8;
typedef __attribute__((ext_vector_type(4))) float f32x4;

DEV unsigned short f2bf(float f){
    unsigned u = __float_as_uint(f);
    u += 0x7FFF + ((u >> 16) & 1);      // RNE
    return (unsigned short)(u >> 16);
}

// ---- problem sizes ----
#define BB 4
#define LL 4096          // H*W, H=W=64
#define DM 96
#define DI 192
#define NS 16
#define KK 4
#define RR 6
#define C38 38
#define NC 64            // chunks
#define CL 64            // chunk length

// ---- workspace layout (float offsets) ----
#define OFF_XIN   0
#define OFF_Z     (OFF_XIN + BB*LL*DI)
#define OFF_XC    (OFF_Z + BB*LL*DI)
#define OFF_DELTA (OFF_XC + BB*LL*DI)
#define OFF_BC    (OFF_DELTA + BB*KK*LL*DI)
#define OFF_YS    (OFF_BC + BB*KK*LL*32)
#define OFF_S     (OFF_YS + BB*KK*LL*DI)
#define OFF_WB    (OFF_S + BB*KK*NC*DI)     // bf16 in_proj weights
#define OFF_CWT   (OFF_WB + 18432)          // transposed conv weights
#define OFF_HLOC  OFF_XIN   // hloc aliases XIN (dead after k_conv)

DEV int pos_of(int k, int t){
    int pr = ((t & 63) << 6) | (t >> 6);
    int p  = (k & 1) ? pr : t;
    if (k & 2) p = LL - 1 - p;
    return p;
}

// ---- 0. prep ----
__global__ __launch_bounds__(256) void k_prep(const float* __restrict__ win, const float* __restrict__ cw,
                                              unsigned short* __restrict__ winb, float* __restrict__ cwT){
    int i = blockIdx.x * 256 + threadIdx.x;
    if (i < 384*DM) winb[i] = f2bf(win[i]);
    if (i < 9*DI){ int tap = i / DI, d = i - tap*DI; cwT[i] = cw[d*9 + tap]; }
}

// ---- 1. in_proj: bf16 MFMA GEMM ----
__global__ __launch_bounds__(256) void k_inproj(const float* __restrict__ x, const unsigned short* __restrict__ winb,
                                                float* __restrict__ xin, float* __restrict__ z){
    __shared__ unsigned short xsb[16*104];
    int tid = threadIdx.x;
    int r0 = blockIdx.x * 16;
    const float* xrow = x + (long)r0 * DM;
    for (int i = tid; i < 16*DM; i += 256){
        int r = i / DM, d = i - r*DM;
        xsb[r*104 + d] = f2bf(xrow[i]);
    }
    __syncthreads();
    int wv = tid >> 6, l = tid & 63;
    int lrow = l & 15, kg = l >> 4;
    int nc0 = wv * 96;
    f32x4 acc[6];
#pragma unroll
    for (int j = 0; j < 6; ++j) acc[j] = (f32x4){0,0,0,0};
    const unsigned short* arow = &xsb[lrow*104 + kg*8];
#pragma unroll
    for (int kk = 0; kk < 3; ++kk){
        bf16x8 af = *(const bf16x8*)(arow + kk*32);
#pragma unroll
        for (int j = 0; j < 6; ++j){
            int col = nc0 + j*16 + lrow;
            bf16x8 bfr = *(const bf16x8*)(winb + (long)col*DM + kg*8 + kk*32);
            acc[j] = __builtin_amdgcn_mfma_f32_16x16x32_bf16(af, bfr, acc[j], 0,0,0);
        }
    }
#pragma unroll
    for (int j = 0; j < 6; ++j){
        int col = nc0 + j*16 + lrow;
#pragma unroll
        for (int reg = 0; reg < 4; ++reg){
            int row = r0 + kg*4 + reg;
            float v = acc[j][reg];
            if (col < DI) xin[(long)row*DI + col] = v;
            else          z[(long)row*DI + (col - DI)] = v;
        }
    }
}

// ---- 2. depthwise conv + SiLU, float4 ----
__global__ __launch_bounds__(256) void k_conv(const float* __restrict__ xin, const float* __restrict__ cwT,
                                              const float* __restrict__ cb, float* __restrict__ xc){
    int g = blockIdx.x * 256 + threadIdx.x;
    int dq = g % 48; int d0 = dq * 4;
    int l = (g / 48) % LL;
    int b = g / (48 * LL);
    int h = l >> 6, wwi = l & 63;
    float4 acc = *(const float4*)(cb + d0);
    const float* base = xin + (long)b * LL * DI + d0;
#pragma unroll
    for (int dy = 0; dy < 3; ++dy){
        int hh = h + dy - 1;
        if (hh < 0 || hh >= 64) continue;
#pragma unroll
        for (int dx = 0; dx < 3; ++dx){
            int wx = wwi + dx - 1;
            if (wx < 0 || wx >= 64) continue;
            float4 xv = *(const float4*)(base + (long)(hh*64 + wx)*DI);
            float4 wv = *(const float4*)(cwT + (dy*3 + dx)*DI + d0);
            acc.x += xv.x*wv.x; acc.y += xv.y*wv.y; acc.z += xv.z*wv.z; acc.w += xv.w*wv.w;
        }
    }
    float4 o;
    o.x = silu(acc.x); o.y = silu(acc.y); o.z = silu(acc.z); o.w = silu(acc.w);
    *(float4*)(xc + ((long)b*LL + l)*DI + d0) = o;
}

// ---- 3. x_proj + dt_proj + softplus — bf16 MFMA GEMM ----
#define XP 200
__global__ __launch_bounds__(256) void k_xdbl(const float* __restrict__ xc, const float* __restrict__ xpw,
                                              const float* __restrict__ dtw, const float* __restrict__ dtb,
                                              float* __restrict__ delta, float* __restrict__ bc2){
    __shared__ unsigned short xsb[64*XP];
    __shared__ unsigned short wsb[48*XP];
    __shared__ float ccs[64][40];
    __shared__ float dtws[DI*RR];
    int tid = threadIdx.x;
    int bk   = blockIdx.x >> 6;
    int tile = blockIdx.x & 63;
    int b = bk >> 2, k = bk & 3;
    int t0 = tile * 64;

    const float* wg = xpw + (long)k * C38 * DI;
    for (int i = tid; i < 48*DI; i += 256){
        int c = i / DI, d = i - c*DI;
        wsb[c*XP + d] = (c < C38) ? f2bf(wg[c*DI + d]) : (unsigned short)0;
    }
    const float* dg = dtw + (long)k * DI * RR;
    for (int i = tid; i < DI*RR; i += 256) dtws[i] = dg[i];
    for (int i = tid; i < 64*DI; i += 256){
        int r = i / DI, d = i - r*DI;
        int p = pos_of(k, t0 + r);
        xsb[r*XP + d] = f2bf(xc[((long)b*LL + p)*DI + d]);
    }
    __syncthreads();

    int wv = tid >> 6, l = tid & 63;
    int lrow = l & 15, kgrp = l >> 4;
    f32x4 acc0 = {0,0,0,0}, acc1 = {0,0,0,0}, acc2 = {0,0,0,0};
    const unsigned short* xrow = &xsb[(wv*16 + lrow)*XP + kgrp*8];
    const unsigned short* wrow = &wsb[lrow*XP + kgrp*8];
#pragma unroll
    for (int kk = 0; kk < 6; ++kk){
        bf16x8 af = *(const bf16x8*)(xrow + kk*32);
        bf16x8 b0 = *(const bf16x8*)(wrow + kk*32);
        bf16x8 b1 = *(const bf16x8*)(wrow + 16*XP + kk*32);
        bf16x8 b2 = *(const bf16x8*)(wrow + 32*XP + kk*32);
        acc0 = __builtin_amdgcn_mfma_f32_16x16x32_bf16(af, b0, acc0, 0,0,0);
        acc1 = __builtin_amdgcn_mfma_f32_16x16x32_bf16(af, b1, acc1, 0,0,0);
        acc2 = __builtin_amdgcn_mfma_f32_16x16x32_bf16(af, b2, acc2, 0,0,0);
    }
#pragma unroll
    for (int reg = 0; reg < 4; ++reg){
        int tl = wv*16 + kgrp*4 + reg;
        ccs[tl][lrow] = acc0[reg];
        ccs[tl][16 + lrow] = acc1[reg];
        if (lrow < 6) ccs[tl][32 + lrow] = acc2[reg];
    }
    __syncthreads();

    long obase = (long)bk * LL + t0;
    for (int i = tid; i < 64*DI; i += 256){
        int r = i / DI, d = i - r*DI;
        float raw = dtb[k*DI + d];
#pragma unroll
        for (int rr = 0; rr < RR; ++rr) raw += ccs[r][rr] * dtws[d*RR + rr];
        float sp = (raw > 15.f) ? raw : __logf(1.f + __expf(raw));
        delta[(obase + r)*DI + d] = sp;
    }
    for (int i = tid; i < 64*32; i += 256){
        int r = i >> 5, q = i & 31;
        bc2[(obase + r)*32 + q] = ccs[r][6 + q];
    }
}

// ---- 4. scan pass A: 192 thr = 192 d, 16 n-states per thread; uniform B row ----
__global__ __launch_bounds__(192) void k_scanA(const float* __restrict__ delta, const float* __restrict__ bc2,
                                               const float* __restrict__ xc, const float* __restrict__ alog,
                                               float* __restrict__ hloc, float* __restrict__ Ssum){
    int d = threadIdx.x;
    int bid = blockIdx.x;
    int c = bid & 63; int bk = bid >> 6;
    int b = bk >> 2, k = bk & 3;
    float a[NS]; bool fast = true;
#pragma unroll
    for (int n = 0; n < NS; ++n){
        a[n] = -__expf(alog[(k*DI + d)*NS + n]);
        fast = fast && (fabsf(a[n] + (float)(n + 1)) < 1e-4f*(float)(n + 1));
    }
    int t0 = c * CL;
    int p0, st;
    if (k == 0){ p0 = t0;         st = 1;   }
    else if (k == 1){ p0 = c;     st = 64;  }
    else if (k == 2){ p0 = LL-1-t0; st = -1;  }
    else            { p0 = LL-1-c;  st = -64; }
    const float* dep = delta + ((long)bk*LL + t0)*DI + d;
    const float* bcp = bc2   + ((long)bk*LL + t0)*32;   // block-uniform
    const float* up  = xc + ((long)b*LL + p0)*DI + d;
    long ustep = (long)st * DI;
    float h[NS];
#pragma unroll
    for (int n = 0; n < NS; ++n) h[n] = 0.f;
    float S = 0.f;
    if (fast){
        float de = *dep, u = *up;
        for (int i = 0; i < CL; ++i){
            dep += DI; up += ustep;
            float de_n = *dep;                      // tail over-read stays in ws
            float u_n  = *up;
            const float4* bq = (const float4*)bcp;  // uniform address -> scalar path
            float4 b0 = bq[0], b1 = bq[1], b2 = bq[2], b3 = bq[3];
            bcp += 32;
            float P[NS];
            P[0] = __expf(-de);
            P[1] = P[0]*P[0];
#pragma unroll
            for (int n = 2; n < NS; ++n) P[n] = P[(n-1)>>1] * P[n-1-((n-1)>>1)];
            float du = de * u;
            S += de;
            float bb[NS] = {b0.x,b0.y,b0.z,b0.w, b1.x,b1.y,b1.z,b1.w,
                            b2.x,b2.y,b2.z,b2.w, b3.x,b3.y,b3.z,b3.w};
#pragma unroll
            for (int n = 0; n < NS; ++n) h[n] = h[n]*P[n] + du*bb[n];
            de = de_n; u = u_n;
        }
    } else {
        for (int i = 0; i < CL; ++i){
            float de = *dep;
            float u  = *up;
            const float4* bq = (const float4*)bcp;
            float4 b0 = bq[0], b1 = bq[1], b2 = bq[2], b3 = bq[3];
            float du = de * u;
            S += de;
            float bb[NS] = {b0.x,b0.y,b0.z,b0.w, b1.x,b1.y,b1.z,b1.w,
                            b2.x,b2.y,b2.z,b2.w, b3.x,b3.y,b3.z,b3.w};
#pragma unroll
            for (int n = 0; n < NS; ++n){ float dA = __expf(de*a[n]); h[n] = h[n]*dA + du*bb[n]; }
            dep += DI; up += ustep; bcp += 32;
        }
    }
    long ho = (((long)bk*NC + c)*DI + d)*NS;
#pragma unroll
    for (int q = 0; q < 4; ++q)
        *(float4*)(hloc + ho + q*4) = make_float4(h[q*4],h[q*4+1],h[q*4+2],h[q*4+3]);
    Ssum[((long)bk*NC + c)*DI + d] = S;
}

// ---- 5. scan pass B: chunk combine, prefetched ----
__global__ __launch_bounds__(256) void k_scanB(float* __restrict__ hloc, const float* __restrict__ Ssum,
                                               const float* __restrict__ alog){
    int gid = blockIdx.x * 256 + threadIdx.x;
    int dn = gid % (DI*NS);
    int bk = gid / (DI*NS);
    int d = dn >> 4, n = dn & 15;
    int k = bk & 3;
    float a = -__expf(alog[(k*DI + d)*NS + n]);
    float h = 0.f;
    long o     = (long)bk * NC * DI * NS + dn;
    long sbase = (long)bk * NC * DI + d;
    float Sc  = Ssum[sbase];
    float tmp = hloc[o];
    for (int c = 0; c < NC; ++c){
        long o_n = o + (long)DI*NS;
        float Sc_n  = Ssum[sbase + (long)(c+1)*DI];   // tail over-read stays in ws
        float tmp_n = hloc[o_n];
        float P = __expf(a * Sc);
        hloc[o] = h;
        h = h * P + tmp;
        o = o_n; Sc = Sc_n; tmp = tmp_n;
    }
}

// ---- 6. scan pass C: 192 thr = 192 d, 16 n-states; in-thread y; coalesced store ----
__global__ __launch_bounds__(192) void k_scanC(const float* __restrict__ delta, const float* __restrict__ bc2,
                                               const float* __restrict__ xc, const float* __restrict__ alog,
                                               const float* __restrict__ hloc, float* __restrict__ ys){
    int d = threadIdx.x;
    int bid = blockIdx.x;
    int c = bid & 63; int bk = bid >> 6;
    int b = bk >> 2, k = bk & 3;
    float a[NS]; bool fast = true;
#pragma unroll
    for (int n = 0; n < NS; ++n){
        a[n] = -__expf(alog[(k*DI + d)*NS + n]);
        fast = fast && (fabsf(a[n] + (float)(n + 1)) < 1e-4f*(float)(n + 1));
    }
    int t0 = c * CL;
    int p0, st;
    if (k == 0){ p0 = t0;         st = 1;   }
    else if (k == 1){ p0 = c;     st = 64;  }
    else if (k == 2){ p0 = LL-1-t0; st = -1;  }
    else            { p0 = LL-1-c;  st = -64; }
    const float* dep = delta + ((long)bk*LL + t0)*DI + d;
    const float* bcp = bc2   + ((long)bk*LL + t0)*32;   // block-uniform
    const float* up  = xc + ((long)b*LL + p0)*DI + d;
    float*       yp  = ys + ((long)bk*LL + p0)*DI + d;
    long ustep = (long)st * DI;
    long ho = (((long)bk*NC + c)*DI + d)*NS;
    float h[NS];
#pragma unroll
    for (int q = 0; q < 4; ++q){
        float4 hv = *(const float4*)(hloc + ho + q*4);
        h[q*4] = hv.x; h[q*4+1] = hv.y; h[q*4+2] = hv.z; h[q*4+3] = hv.w;
    }
    if (fast){
        float de = *dep, u = *up;
        for (int i = 0; i < CL; ++i){
            dep += DI; up += ustep;
            float de_n = *dep;
            float u_n  = *up;
            const float4* bq = (const float4*)bcp;
            float4 b0 = bq[0], b1 = bq[1], b2 = bq[2], b3 = bq[3];
            float4 c0 = bq[4], c1 = bq[5], c2 = bq[6], c3 = bq[7];
            bcp += 32;
            float P[NS];
            P[0] = __expf(-de);
            P[1] = P[0]*P[0];
#pragma unroll
            for (int n = 2; n < NS; ++n) P[n] = P[(n-1)>>1] * P[n-1-((n-1)>>1)];
            float du = de * u;
            float bb[NS] = {b0.x,b0.y,b0.z,b0.w, b1.x,b1.y,b1.z,b1.w,
                            b2.x,b2.y,b2.z,b2.w, b3.x,b3.y,b3.z,b3.w};
            float cc[NS] = {c0.x,c0.y,c0.z,c0.w, c1.x,c1.y,c1.z,c1.w,
                            c2.x,c2.y,c2.z,c2.w, c3.x,c3.y,c3.z,c3.w};
            float y = 0.f;
#pragma unroll
            for (int n = 0; n < NS; ++n){ h[n] = h[n]*P[n] + du*bb[n]; y += h[n]*cc[n]; }
            *yp = y;
            yp += ustep;
            de = de_n; u = u_n;
        }
    } else {
        for (int i = 0; i < CL; ++i){
            float de = *dep;
            float u  = *up;
            const float4* bq = (const float4*)bcp;
            float4 b0 = bq[0], b1 = bq[1], b2 = bq[2], b3 = bq[3];
            float4 c0 = bq[4], c1 = bq[5], c2 = bq[6], c3 = bq[7];
            float du = de * u;
            float bb[NS] = {b0.x,b0.y,b0.z,b0.w, b1.x,b1.y,b1.z,b1.w,
                            b2.x,b2.y,b2.z,b2.w, b3.x,b3.y,b3.z,b3.w};
            float cc[NS] = {c0.x,c0.y,c0.z,c0.w, c1.x,c1.y,c1.z,c1.w,
                            c2.x,c2.y,c2.z,c2.w, c3.x,c3.y,c3.z,c3.w};
            float y = 0.f;
#pragma unroll
            for (int n = 0; n < NS; ++n){ float dA = __expf(de*a[n]); h[n] = h[n]*dA + du*bb[n]; y += h[n]*cc[n]; }
            *yp = y;
            dep += DI; up += ustep; yp += ustep; bcp += 32;
        }
    }
}

// ---- 7. merge + LN + gate + out_proj ----
__global__ __launch_bounds__(192) void k_fuse(const float* __restrict__ ys, const float* __restrict__ xc,
                                              const float* __restrict__ z, const float* __restrict__ Dsk,
                                              const float* __restrict__ lnw, const float* __restrict__ lnb,
                                              const float* __restrict__ wout, float* __restrict__ out){
    __shared__ float yv[4][DI];
    __shared__ float red[2][3];
    __shared__ float part[2][4][96];
    int tid = threadIdx.x;
    int b  = blockIdx.x / (LL/4);
    int p0 = (blockIdx.x % (LL/4)) * 4;
    int d = tid;
    float sumD = Dsk[d] + Dsk[DI + d] + Dsk[2*DI + d] + Dsk[3*DI + d];
    float lw = lnw[d], lb = lnb[d];
    for (int pp = 0; pp < 4; ++pp){
        int p = p0 + pp;
        long yb = ((long)b*4)*LL*DI + (long)p*DI + d;
        float y = ys[yb] + ys[yb + (long)LL*DI] + ys[yb + 2L*LL*DI] + ys[yb + 3L*LL*DI];
        y += xc[((long)b*LL + p)*DI + d] * sumD;
        float s = y, sq = y*y;
#pragma unroll
        for (int m = 32; m > 0; m >>= 1){ s += __shfl_down(s, m, 64); sq += __shfl_down(sq, m, 64); }
        int wvi = tid >> 6, ln = tid & 63;
        if (ln == 0){ red[0][wvi] = s; red[1][wvi] = sq; }
        __syncthreads();
        float st  = red[0][0] + red[0][1] + red[0][2];
        float sqt = red[1][0] + red[1][1] + red[1][2];
        float mu  = st / DI;
        float var = sqt / DI - mu*mu;
        float rs  = rsqrtf(var + 1e-5f);
        float yn  = (y - mu)*rs*lw + lb;
        float zg  = z[((long)b*LL + p)*DI + d];
        yv[pp][d] = yn * silu(zg);
        __syncthreads();
    }
    int m = tid % 96, half = tid / 96;
    float acc[4] = {0.f, 0.f, 0.f, 0.f};
    const float* wr = wout + (long)m*DI + half*96;
    for (int dd = 0; dd < 96; ++dd){
        float wv = wr[dd];
        int df = half*96 + dd;
#pragma unroll
        for (int pp = 0; pp < 4; ++pp) acc[pp] += wv * yv[pp][df];
    }
#pragma unroll
    for (int pp = 0; pp < 4; ++pp) part[half][pp][m] = acc[pp];
    __syncthreads();
    if (tid < 96){
#pragma unroll
        for (int pp = 0; pp < 4; ++pp){
            float v = part[0][pp][tid] + part[1][pp][tid];
            out[((long)b*LL + p0 + pp)*DM + tid] = v;
        }
    }
}

extern "C" void kernel_launch(void* const* d_in, const int* in_sizes, int n_in,
                              void* d_out, int out_size, void* d_ws, size_t ws_size,
                              hipStream_t stream){
    (void)in_sizes; (void)n_in; (void)out_size; (void)ws_size;
    const float* x    = (const float*)d_in[0];
    const float* win  = (const float*)d_in[1];
    const float* cw   = (const float*)d_in[2];
    const float* cb   = (const float*)d_in[3];
    const float* xpw  = (const float*)d_in[4];
    const float* dtw  = (const float*)d_in[5];
    const float* dtb  = (const float*)d_in[6];
    const float* alog = (const float*)d_in[7];
    const float* ds   = (const float*)d_in[8];
    const float* lnw  = (const float*)d_in[9];
    const float* lnb  = (const float*)d_in[10];
    const float* wout = (const float*)d_in[11];

    float* ws    = (float*)d_ws;
    float* xin   = ws + OFF_XIN;
    float* z     = ws + OFF_Z;
    float* xc    = ws + OFF_XC;
    float* delta = ws + OFF_DELTA;
    float* bc2   = ws + OFF_BC;
    float* ysb   = ws + OFF_YS;
    float* Ssum  = ws + OFF_S;
    unsigned short* winb = (unsigned short*)(ws + OFF_WB);
    float* cwT   = ws + OFF_CWT;
    float* hloc  = ws + OFF_HLOC;

    k_prep  <<<dim3(144),  dim3(256), 0, stream>>>(win, cw, winb, cwT);
    k_inproj<<<dim3(1024), dim3(256), 0, stream>>>(x, winb, xin, z);
    k_conv  <<<dim3(3072), dim3(256), 0, stream>>>(xin, cwT, cb, xc);
    k_xdbl  <<<dim3(1024), dim3(256), 0, stream>>>(xc, xpw, dtw, dtb, delta, bc2);
    k_scanA <<<dim3(1024), dim3(192), 0, stream>>>(delta, bc2, xc, alog, hloc, Ssum);
    k_scanB <<<dim3(192),  dim3(256), 0, stream>>>(hloc, Ssum, alog);
    k_scanC <<<dim3(1024), dim3(192), 0, stream>>>(delta, bc2, xc, alog, hloc, ysb);
    k_fuse  <<<dim3(4096), dim3(192), 0, stream>>>(ysb, xc, z, ds, lnw, lnb, wout,
                                                   (float*)d_out);
}

// Round 10
// 212.775 us; speedup vs baseline: 1.4604x; 1.0389x over previous
//
#include <hip/hip_runtime.h>
#include <hip/hip_bf16.h>

#define DEV static __device__ __forceinline__

DEV float silu(float x){ return x / (1.f + __expf(-x)); }

typedef __attribute__((ext_vector_type(8))) short bf16x8;
typedef __attribute__((ext_vector_type(4))) float f32x4;

DEV unsigned short f2bf(float f){
    unsigned u = __float_as_uint(f);
    u += 0x7FFF + ((u >> 16) & 1);      // RNE
    return (unsigned short)(u >> 16);
}

// ---- problem sizes ----
#define BB 4
#define LL 4096          // H*W, H=W=64
#define DM 96
#define DI 192
#define NS 16
#define KK 4
#define RR 6
#define C38 38
#define NC 64            // chunks
#define CL 64            // chunk length
#define NCOMB 224        // combined x_proj/dt_proj output rows: 192 delta + 32 B/C

// ---- workspace layout (float offsets) ----
#define OFF_XIN   0
#define OFF_Z     (OFF_XIN + BB*LL*DI)
#define OFF_XC    (OFF_Z + BB*LL*DI)
#define OFF_DELTA (OFF_XC + BB*LL*DI)
#define OFF_BC    (OFF_DELTA + BB*KK*LL*DI)
#define OFF_YS    (OFF_BC + BB*KK*LL*32)
#define OFF_S     (OFF_YS + BB*KK*LL*DI)
#define OFF_WB    (OFF_S + BB*KK*NC*DI)         // bf16 in_proj weights (384*96 u16)
#define OFF_CWT   (OFF_WB + 18432)              // transposed conv weights (9*192 f32)
#define OFF_WC    (OFF_CWT + 1728)              // bf16 combined x/dt proj weights (4*224*192 u16)
#define OFF_HLOC  OFF_XIN   // hloc aliases XIN (dead after k_conv)

DEV int pos_of(int k, int t){
    int pr = ((t & 63) << 6) | (t >> 6);
    int p  = (k & 1) ? pr : t;
    if (k & 2) p = LL - 1 - p;
    return p;
}

// ---- 0. prep: winb bf16; cw transpose; W_comb = [dtw@xpw[0:6] ; xpw[6:38]] bf16 ----
__global__ __launch_bounds__(256) void k_prep(const float* __restrict__ win, const float* __restrict__ cw,
                                              const float* __restrict__ xpw, const float* __restrict__ dtw,
                                              unsigned short* __restrict__ winb, float* __restrict__ cwT,
                                              unsigned short* __restrict__ wcomb){
    int i = blockIdx.x * 256 + threadIdx.x;
    if (i < 384*DM) winb[i] = f2bf(win[i]);
    if (i < 9*DI){ int tap = i / DI, d = i - tap*DI; cwT[i] = cw[d*9 + tap]; }
    if (i < KK*NCOMB*DI){
        int kk = i % DI; int j = (i / DI) % NCOMB; int k = i / (DI*NCOMB);
        float v;
        if (j < DI){
            v = 0.f;
            const float* dtwp = dtw + ((long)k*DI + j)*RR;
            const float* xp   = xpw + (long)k*C38*DI + kk;
#pragma unroll
            for (int r = 0; r < RR; ++r) v += dtwp[r] * xp[(long)r*DI];
        } else {
            v = xpw[(long)k*C38*DI + (long)(6 + j - DI)*DI + kk];
        }
        wcomb[i] = f2bf(v);
    }
}

// ---- 1. in_proj: bf16 MFMA GEMM ----
__global__ __launch_bounds__(256) void k_inproj(const float* __restrict__ x, const unsigned short* __restrict__ winb,
                                                float* __restrict__ xin, float* __restrict__ z){
    __shared__ unsigned short xsb[16*104];
    int tid = threadIdx.x;
    int r0 = blockIdx.x * 16;
    const float* xrow = x + (long)r0 * DM;
    for (int i = tid; i < 16*DM; i += 256){
        int r = i / DM, d = i - r*DM;
        xsb[r*104 + d] = f2bf(xrow[i]);
    }
    __syncthreads();
    int wv = tid >> 6, l = tid & 63;
    int lrow = l & 15, kg = l >> 4;
    int nc0 = wv * 96;
    f32x4 acc[6];
#pragma unroll
    for (int j = 0; j < 6; ++j) acc[j] = (f32x4){0,0,0,0};
    const unsigned short* arow = &xsb[lrow*104 + kg*8];
#pragma unroll
    for (int kk = 0; kk < 3; ++kk){
        bf16x8 af = *(const bf16x8*)(arow + kk*32);
#pragma unroll
        for (int j = 0; j < 6; ++j){
            int col = nc0 + j*16 + lrow;
            bf16x8 bfr = *(const bf16x8*)(winb + (long)col*DM + kg*8 + kk*32);
            acc[j] = __builtin_amdgcn_mfma_f32_16x16x32_bf16(af, bfr, acc[j], 0,0,0);
        }
    }
#pragma unroll
    for (int j = 0; j < 6; ++j){
        int col = nc0 + j*16 + lrow;
#pragma unroll
        for (int reg = 0; reg < 4; ++reg){
            int row = r0 + kg*4 + reg;
            float v = acc[j][reg];
            if (col < DI) xin[(long)row*DI + col] = v;
            else          z[(long)row*DI + (col - DI)] = v;
        }
    }
}

// ---- 2. depthwise conv + SiLU, float4 ----
__global__ __launch_bounds__(256) void k_conv(const float* __restrict__ xin, const float* __restrict__ cwT,
                                              const float* __restrict__ cb, float* __restrict__ xc){
    int g = blockIdx.x * 256 + threadIdx.x;
    int dq = g % 48; int d0 = dq * 4;
    int l = (g / 48) % LL;
    int b = g / (48 * LL);
    int h = l >> 6, wwi = l & 63;
    float4 acc = *(const float4*)(cb + d0);
    const float* base = xin + (long)b * LL * DI + d0;
#pragma unroll
    for (int dy = 0; dy < 3; ++dy){
        int hh = h + dy - 1;
        if (hh < 0 || hh >= 64) continue;
#pragma unroll
        for (int dx = 0; dx < 3; ++dx){
            int wx = wwi + dx - 1;
            if (wx < 0 || wx >= 64) continue;
            float4 xv = *(const float4*)(base + (long)(hh*64 + wx)*DI);
            float4 wv = *(const float4*)(cwT + (dy*3 + dx)*DI + d0);
            acc.x += xv.x*wv.x; acc.y += xv.y*wv.y; acc.z += xv.z*wv.z; acc.w += xv.w*wv.w;
        }
    }
    float4 o;
    o.x = silu(acc.x); o.y = silu(acc.y); o.z = silu(acc.z); o.w = silu(acc.w);
    *(float4*)(xc + ((long)b*LL + l)*DI + d0) = o;
}

// ---- 3. x_proj+dt_proj fused GEMM: M=64, N=224, K=192; softplus in registers ----
#define XP 200
__global__ __launch_bounds__(512) void k_xdbl(const float* __restrict__ xc, const unsigned short* __restrict__ wcomb,
                                              const float* __restrict__ dtb,
                                              float* __restrict__ delta, float* __restrict__ bc2){
    __shared__ unsigned short xsb[64*XP];   // 25.6KB only
    int tid = threadIdx.x;
    int bk   = blockIdx.x >> 6;
    int tile = blockIdx.x & 63;
    int b = bk >> 2, k = bk & 3;
    int t0 = tile * 64;
    for (int i = tid; i < 64*DI; i += 512){
        int r = i / DI, d = i - r*DI;
        int p = pos_of(k, t0 + r);
        xsb[r*XP + d] = f2bf(xc[((long)b*LL + p)*DI + d]);
    }
    __syncthreads();

    int wv = tid >> 6, l = tid & 63;
    int lrow = l & 15, kgrp = l >> 4;
    int rt = wv & 3, ch = wv >> 2;       // row-tile 0..3, col-half 0..1 (112 cols each)
    f32x4 acc[7];
#pragma unroll
    for (int j = 0; j < 7; ++j) acc[j] = (f32x4){0,0,0,0};
    const unsigned short* arow = &xsb[(rt*16 + lrow)*XP + kgrp*8];
    const unsigned short* wb = wcomb + (long)k*NCOMB*DI + ((long)ch*112 + lrow)*DI + kgrp*8;
#pragma unroll
    for (int ks = 0; ks < 6; ++ks){
        bf16x8 af = *(const bf16x8*)(arow + ks*32);
#pragma unroll
        for (int nt = 0; nt < 7; ++nt){
            bf16x8 bfr = *(const bf16x8*)(wb + (long)nt*16*DI + ks*32);
            acc[nt] = __builtin_amdgcn_mfma_f32_16x16x32_bf16(af, bfr, acc[nt], 0,0,0);
        }
    }
    // C/D: col = lane&15 within tile, row = kgrp*4 + reg
    long obase = (long)bk*LL + t0 + rt*16 + kgrp*4;
#pragma unroll
    for (int nt = 0; nt < 7; ++nt){
        int col = ch*112 + nt*16 + lrow;
        if (col < DI){
            float bias = dtb[k*DI + col];
#pragma unroll
            for (int reg = 0; reg < 4; ++reg){
                float raw = acc[nt][reg] + bias;
                float sp = (raw > 15.f) ? raw : __logf(1.f + __expf(raw));
                delta[(obase + reg)*DI + col] = sp;
            }
        } else {
            int q = col - DI;
#pragma unroll
            for (int reg = 0; reg < 4; ++reg)
                bc2[(obase + reg)*32 + q] = acc[nt][reg];
        }
    }
}

// ---- 4. scan pass A: 192 thr = 192 d, 16 n-states per thread; uniform B row ----
__global__ __launch_bounds__(192) void k_scanA(const float* __restrict__ delta, const float* __restrict__ bc2,
                                               const float* __restrict__ xc, const float* __restrict__ alog,
                                               float* __restrict__ hloc, float* __restrict__ Ssum){
    int d = threadIdx.x;
    int bid = blockIdx.x;
    int c = bid & 63; int bk = bid >> 6;
    int b = bk >> 2, k = bk & 3;
    float a[NS]; bool fast = true;
#pragma unroll
    for (int n = 0; n < NS; ++n){
        a[n] = -__expf(alog[(k*DI + d)*NS + n]);
        fast = fast && (fabsf(a[n] + (float)(n + 1)) < 1e-4f*(float)(n + 1));
    }
    int t0 = c * CL;
    int p0, st;
    if (k == 0){ p0 = t0;         st = 1;   }
    else if (k == 1){ p0 = c;     st = 64;  }
    else if (k == 2){ p0 = LL-1-t0; st = -1;  }
    else            { p0 = LL-1-c;  st = -64; }
    const float* dep = delta + ((long)bk*LL + t0)*DI + d;
    const float* bcp = bc2   + ((long)bk*LL + t0)*32;   // block-uniform
    const float* up  = xc + ((long)b*LL + p0)*DI + d;
    long ustep = (long)st * DI;
    float h[NS];
#pragma unroll
    for (int n = 0; n < NS; ++n) h[n] = 0.f;
    float S = 0.f;
    if (fast){
        float de = *dep, u = *up;
        for (int i = 0; i < CL; ++i){
            dep += DI; up += ustep;
            float de_n = *dep;                      // tail over-read stays in ws
            float u_n  = *up;
            const float4* bq = (const float4*)bcp;  // uniform address -> scalar path
            float4 b0 = bq[0], b1 = bq[1], b2 = bq[2], b3 = bq[3];
            bcp += 32;
            float P[NS];
            P[0] = __expf(-de);
            P[1] = P[0]*P[0];
#pragma unroll
            for (int n = 2; n < NS; ++n) P[n] = P[(n-1)>>1] * P[n-1-((n-1)>>1)];
            float du = de * u;
            S += de;
            float bb[NS] = {b0.x,b0.y,b0.z,b0.w, b1.x,b1.y,b1.z,b1.w,
                            b2.x,b2.y,b2.z,b2.w, b3.x,b3.y,b3.z,b3.w};
#pragma unroll
            for (int n = 0; n < NS; ++n) h[n] = h[n]*P[n] + du*bb[n];
            de = de_n; u = u_n;
        }
    } else {
        for (int i = 0; i < CL; ++i){
            float de = *dep;
            float u  = *up;
            const float4* bq = (const float4*)bcp;
            float4 b0 = bq[0], b1 = bq[1], b2 = bq[2], b3 = bq[3];
            float du = de * u;
            S += de;
            float bb[NS] = {b0.x,b0.y,b0.z,b0.w, b1.x,b1.y,b1.z,b1.w,
                            b2.x,b2.y,b2.z,b2.w, b3.x,b3.y,b3.z,b3.w};
#pragma unroll
            for (int n = 0; n < NS; ++n){ float dA = __expf(de*a[n]); h[n] = h[n]*dA + du*bb[n]; }
            dep += DI; up += ustep; bcp += 32;
        }
    }
    long ho = (((long)bk*NC + c)*DI + d)*NS;
#pragma unroll
    for (int q = 0; q < 4; ++q)
        *(float4*)(hloc + ho + q*4) = make_float4(h[q*4],h[q*4+1],h[q*4+2],h[q*4+3]);
    Ssum[((long)bk*NC + c)*DI + d] = S;
}

// ---- 5. scan pass B: chunk combine, prefetched ----
__global__ __launch_bounds__(256) void k_scanB(float* __restrict__ hloc, const float* __restrict__ Ssum,
                                               const float* __restrict__ alog){
    int gid = blockIdx.x * 256 + threadIdx.x;
    int dn = gid % (DI*NS);
    int bk = gid / (DI*NS);
    int d = dn >> 4, n = dn & 15;
    int k = bk & 3;
    float a = -__expf(alog[(k*DI + d)*NS + n]);
    float h = 0.f;
    long o     = (long)bk * NC * DI * NS + dn;
    long sbase = (long)bk * NC * DI + d;
    float Sc  = Ssum[sbase];
    float tmp = hloc[o];
    for (int c = 0; c < NC; ++c){
        long o_n = o + (long)DI*NS;
        float Sc_n  = Ssum[sbase + (long)(c+1)*DI];   // tail over-read stays in ws
        float tmp_n = hloc[o_n];
        float P = __expf(a * Sc);
        hloc[o] = h;
        h = h * P + tmp;
        o = o_n; Sc = Sc_n; tmp = tmp_n;
    }
}

// ---- 6. scan pass C: 192 thr = 192 d, 16 n-states; in-thread y; coalesced store ----
__global__ __launch_bounds__(192) void k_scanC(const float* __restrict__ delta, const float* __restrict__ bc2,
                                               const float* __restrict__ xc, const float* __restrict__ alog,
                                               const float* __restrict__ hloc, float* __restrict__ ys){
    int d = threadIdx.x;
    int bid = blockIdx.x;
    int c = bid & 63; int bk = bid >> 6;
    int b = bk >> 2, k = bk & 3;
    float a[NS]; bool fast = true;
#pragma unroll
    for (int n = 0; n < NS; ++n){
        a[n] = -__expf(alog[(k*DI + d)*NS + n]);
        fast = fast && (fabsf(a[n] + (float)(n + 1)) < 1e-4f*(float)(n + 1));
    }
    int t0 = c * CL;
    int p0, st;
    if (k == 0){ p0 = t0;         st = 1;   }
    else if (k == 1){ p0 = c;     st = 64;  }
    else if (k == 2){ p0 = LL-1-t0; st = -1;  }
    else            { p0 = LL-1-c;  st = -64; }
    const float* dep = delta + ((long)bk*LL + t0)*DI + d;
    const float* bcp = bc2   + ((long)bk*LL + t0)*32;   // block-uniform
    const float* up  = xc + ((long)b*LL + p0)*DI + d;
    float*       yp  = ys + ((long)bk*LL + p0)*DI + d;
    long ustep = (long)st * DI;
    long ho = (((long)bk*NC + c)*DI + d)*NS;
    float h[NS];
#pragma unroll
    for (int q = 0; q < 4; ++q){
        float4 hv = *(const float4*)(hloc + ho + q*4);
        h[q*4] = hv.x; h[q*4+1] = hv.y; h[q*4+2] = hv.z; h[q*4+3] = hv.w;
    }
    if (fast){
        float de = *dep, u = *up;
        for (int i = 0; i < CL; ++i){
            dep += DI; up += ustep;
            float de_n = *dep;
            float u_n  = *up;
            const float4* bq = (const float4*)bcp;
            float4 b0 = bq[0], b1 = bq[1], b2 = bq[2], b3 = bq[3];
            float4 c0 = bq[4], c1 = bq[5], c2 = bq[6], c3 = bq[7];
            bcp += 32;
            float P[NS];
            P[0] = __expf(-de);
            P[1] = P[0]*P[0];
#pragma unroll
            for (int n = 2; n < NS; ++n) P[n] = P[(n-1)>>1] * P[n-1-((n-1)>>1)];
            float du = de * u;
            float bb[NS] = {b0.x,b0.y,b0.z,b0.w, b1.x,b1.y,b1.z,b1.w,
                            b2.x,b2.y,b2.z,b2.w, b3.x,b3.y,b3.z,b3.w};
            float cc[NS] = {c0.x,c0.y,c0.z,c0.w, c1.x,c1.y,c1.z,c1.w,
                            c2.x,c2.y,c2.z,c2.w, c3.x,c3.y,c3.z,c3.w};
            float y = 0.f;
#pragma unroll
            for (int n = 0; n < NS; ++n){ h[n] = h[n]*P[n] + du*bb[n]; y += h[n]*cc[n]; }
            *yp = y;
            yp += ustep;
            de = de_n; u = u_n;
        }
    } else {
        for (int i = 0; i < CL; ++i){
            float de = *dep;
            float u  = *up;
            const float4* bq = (const float4*)bcp;
            float4 b0 = bq[0], b1 = bq[1], b2 = bq[2], b3 = bq[3];
            float4 c0 = bq[4], c1 = bq[5], c2 = bq[6], c3 = bq[7];
            float du = de * u;
            float bb[NS] = {b0.x,b0.y,b0.z,b0.w, b1.x,b1.y,b1.z,b1.w,
                            b2.x,b2.y,b2.z,b2.w, b3.x,b3.y,b3.z,b3.w};
            float cc[NS] = {c0.x,c0.y,c0.z,c0.w, c1.x,c1.y,c1.z,c1.w,
                            c2.x,c2.y,c2.z,c2.w, c3.x,c3.y,c3.z,c3.w};
            float y = 0.f;
#pragma unroll
            for (int n = 0; n < NS; ++n){ float dA = __expf(de*a[n]); h[n] = h[n]*dA + du*bb[n]; y += h[n]*cc[n]; }
            *yp = y;
            dep += DI; up += ustep; yp += ustep; bcp += 32;
        }
    }
}

// ---- 7. merge + LN + gate + out_proj ----
__global__ __launch_bounds__(192) void k_fuse(const float* __restrict__ ys, const float* __restrict__ xc,
                                              const float* __restrict__ z, const float* __restrict__ Dsk,
                                              const float* __restrict__ lnw, const float* __restrict__ lnb,
                                              const float* __restrict__ wout, float* __restrict__ out){
    __shared__ float yv[4][DI];
    __shared__ float red[2][3];
    __shared__ float part[2][4][96];
    int tid = threadIdx.x;
    int b  = blockIdx.x / (LL/4);
    int p0 = (blockIdx.x % (LL/4)) * 4;
    int d = tid;
    float sumD = Dsk[d] + Dsk[DI + d] + Dsk[2*DI + d] + Dsk[3*DI + d];
    float lw = lnw[d], lb = lnb[d];
    for (int pp = 0; pp < 4; ++pp){
        int p = p0 + pp;
        long yb = ((long)b*4)*LL*DI + (long)p*DI + d;
        float y = ys[yb] + ys[yb + (long)LL*DI] + ys[yb + 2L*LL*DI] + ys[yb + 3L*LL*DI];
        y += xc[((long)b*LL + p)*DI + d] * sumD;
        float s = y, sq = y*y;
#pragma unroll
        for (int m = 32; m > 0; m >>= 1){ s += __shfl_down(s, m, 64); sq += __shfl_down(sq, m, 64); }
        int wvi = tid >> 6, ln = tid & 63;
        if (ln == 0){ red[0][wvi] = s; red[1][wvi] = sq; }
        __syncthreads();
        float st  = red[0][0] + red[0][1] + red[0][2];
        float sqt = red[1][0] + red[1][1] + red[1][2];
        float mu  = st / DI;
        float var = sqt / DI - mu*mu;
        float rs  = rsqrtf(var + 1e-5f);
        float yn  = (y - mu)*rs*lw + lb;
        float zg  = z[((long)b*LL + p)*DI + d];
        yv[pp][d] = yn * silu(zg);
        __syncthreads();
    }
    int m = tid % 96, half = tid / 96;
    float acc[4] = {0.f, 0.f, 0.f, 0.f};
    const float* wr = wout + (long)m*DI + half*96;
    for (int dd = 0; dd < 96; ++dd){
        float wv = wr[dd];
        int df = half*96 + dd;
#pragma unroll
        for (int pp = 0; pp < 4; ++pp) acc[pp] += wv * yv[pp][df];
    }
#pragma unroll
    for (int pp = 0; pp < 4; ++pp) part[half][pp][m] = acc[pp];
    __syncthreads();
    if (tid < 96){
#pragma unroll
        for (int pp = 0; pp < 4; ++pp){
            float v = part[0][pp][tid] + part[1][pp][tid];
            out[((long)b*LL + p0 + pp)*DM + tid] = v;
        }
    }
}

extern "C" void kernel_launch(void* const* d_in, const int* in_sizes, int n_in,
                              void* d_out, int out_size, void* d_ws, size_t ws_size,
                              hipStream_t stream){
    (void)in_sizes; (void)n_in; (void)out_size; (void)ws_size;
    const float* x    = (const float*)d_in[0];
    const float* win  = (const float*)d_in[1];
    const float* cw   = (const float*)d_in[2];
    const float* cb   = (const float*)d_in[3];
    const float* xpw  = (const float*)d_in[4];
    const float* dtw  = (const float*)d_in[5];
    const float* dtb  = (const float*)d_in[6];
    const float* alog = (const float*)d_in[7];
    const float* ds   = (const float*)d_in[8];
    const float* lnw  = (const float*)d_in[9];
    const float* lnb  = (const float*)d_in[10];
    const float* wout = (const float*)d_in[11];

    float* ws    = (float*)d_ws;
    float* xin   = ws + OFF_XIN;
    float* z     = ws + OFF_Z;
    float* xc    = ws + OFF_XC;
    float* delta = ws + OFF_DELTA;
    float* bc2   = ws + OFF_BC;
    float* ysb   = ws + OFF_YS;
    float* Ssum  = ws + OFF_S;
    unsigned short* winb  = (unsigned short*)(ws + OFF_WB);
    float* cwT   = ws + OFF_CWT;
    unsigned short* wcomb = (unsigned short*)(ws + OFF_WC);
    float* hloc  = ws + OFF_HLOC;

    k_prep  <<<dim3(672),  dim3(256), 0, stream>>>(win, cw, xpw, dtw, winb, cwT, wcomb);
    k_inproj<<<dim3(1024), dim3(256), 0, stream>>>(x, winb, xin, z);
    k_conv  <<<dim3(3072), dim3(256), 0, stream>>>(xin, cwT, cb, xc);
    k_xdbl  <<<dim3(1024), dim3(512), 0, stream>>>(xc, wcomb, dtb, delta, bc2);
    k_scanA <<<dim3(1024), dim3(192), 0, stream>>>(delta, bc2, xc, alog, hloc, Ssum);
    k_scanB <<<dim3(192),  dim3(256), 0, stream>>>(hloc, Ssum, alog);
    k_scanC <<<dim3(1024), dim3(192), 0, stream>>>(delta, bc2, xc, alog, hloc, ysb);
    k_fuse  <<<dim3(4096), dim3(192), 0, stream>>>(ysb, xc, z, ds, lnw, lnb, wout,
                                                   (float*)d_out);
}